// Round 1
// baseline (1001.064 us; speedup 1.0000x reference)
//
#include <hip/hip_runtime.h>
#include <hip/hip_bf16.h>
#include <math.h>

// Problem constants (B,N,D,S,H from reference setup_inputs)
#define Bn 64
#define Nn 4096
#define Dn 128
#define Sn 8
#define Hn 256
#define LN_EPS 1e-5f

__device__ __forceinline__ float dot4(float4 a, float4 b) {
    return a.x*b.x + a.y*b.y + a.z*b.z + a.w*b.w;
}

// ---------------------------------------------------------------------------
// K0: slots = mu + exp(log_sigma) * noise, broadcast over batch
__global__ void k_slots_init(const float* __restrict__ mu, const float* __restrict__ ls,
                             const float* __restrict__ noise, float* __restrict__ slots) {
    int i = blockIdx.x * blockDim.x + threadIdx.x;  // over S*D = 1024
    if (i < Sn * Dn) {
        float v = mu[i] + __expf(ls[i]) * noise[i];
        #pragma unroll 4
        for (int b = 0; b < Bn; ++b) slots[b * Sn * Dn + i] = v;
    }
}

// ---------------------------------------------------------------------------
// K1: x = LN(inputs)*g+b; k = x@wk.T+bk; v = x@wv.T+bv
// One block = 64 rows; 256 threads; thread = 4 cols x 16 rows register tile.
__global__ __launch_bounds__(256) void k_lnkv(
    const float* __restrict__ inp, const float* __restrict__ ni_g, const float* __restrict__ ni_b,
    const float* __restrict__ wk, const float* __restrict__ bk,
    const float* __restrict__ wv, const float* __restrict__ bv,
    float* __restrict__ kout, float* __restrict__ vout)
{
    __shared__ float xs[64 * 128];   // 32 KiB: raw x, then normalized in place
    __shared__ float stats[64 * 2];  // mean, rstd per row
    __shared__ float gb[256];        // g then b
    const int t = threadIdx.x;
    const int rowbase = blockIdx.x * 64;  // over B*N = 262144 rows
    const float* src = inp + (size_t)rowbase * Dn;

    gb[t] = (t < 128) ? ni_g[t] : ni_b[t - 128];

    // Coalesced float4 tile load + per-row sum/sumsq via 32-lane xor-reduce.
    // float4 index f = it*256+t -> row f>>5 (32 consecutive lanes share a row).
    #pragma unroll
    for (int it = 0; it < 8; ++it) {
        int f = it * 256 + t;
        float4 x4 = ((const float4*)src)[f];
        ((float4*)xs)[f] = x4;
        float s  = x4.x + x4.y + x4.z + x4.w;
        float sq = x4.x*x4.x + x4.y*x4.y + x4.z*x4.z + x4.w*x4.w;
        #pragma unroll
        for (int m = 1; m <= 16; m <<= 1) { s += __shfl_xor(s, m); sq += __shfl_xor(sq, m); }
        if ((t & 31) == 0) {
            int r = it * 8 + (t >> 5);
            float mu  = s * (1.0f / 128.0f);
            float var = sq * (1.0f / 128.0f) - mu * mu;
            stats[2 * r]     = mu;
            stats[2 * r + 1] = rsqrtf(var + LN_EPS);
        }
    }
    __syncthreads();
    // Normalize in place
    #pragma unroll
    for (int it = 0; it < 8; ++it) {
        int f = it * 256 + t;
        int r = f >> 5;
        int c = (f & 31) * 4;
        float mu = stats[2 * r], rs = stats[2 * r + 1];
        float4 x4 = ((float4*)xs)[f];
        x4.x = (x4.x - mu) * rs * gb[c + 0] + gb[128 + c + 0];
        x4.y = (x4.y - mu) * rs * gb[c + 1] + gb[128 + c + 1];
        x4.z = (x4.z - mu) * rs * gb[c + 2] + gb[128 + c + 2];
        x4.w = (x4.w - mu) * rs * gb[c + 3] + gb[128 + c + 3];
        ((float4*)xs)[f] = x4;
    }
    __syncthreads();

    // Matvec: thread handles cols c0..c0+3 (0..127 -> k, 128..255 -> v), rows 16*rg..+15
    const int cg = t & 63;
    const int rg = t >> 6;
    const int c0 = cg * 4;
    const bool is_k = (c0 < 128);
    const float* W   = is_k ? (wk + (size_t)c0 * Dn) : (wv + (size_t)(c0 - 128) * Dn);
    const float* bia = is_k ? (bk + c0) : (bv + (c0 - 128));
    float acc[16][4];
    #pragma unroll
    for (int i = 0; i < 16; ++i) { acc[i][0]=0.f; acc[i][1]=0.f; acc[i][2]=0.f; acc[i][3]=0.f; }

    for (int d = 0; d < 128; d += 4) {
        float4 w0 = *(const float4*)(W + 0 * Dn + d);
        float4 w1 = *(const float4*)(W + 1 * Dn + d);
        float4 w2 = *(const float4*)(W + 2 * Dn + d);
        float4 w3 = *(const float4*)(W + 3 * Dn + d);
        #pragma unroll
        for (int i = 0; i < 16; ++i) {
            float4 x4 = *(const float4*)&xs[(16 * rg + i) * 128 + d];  // wave-uniform broadcast
            acc[i][0] += dot4(x4, w0);
            acc[i][1] += dot4(x4, w1);
            acc[i][2] += dot4(x4, w2);
            acc[i][3] += dot4(x4, w3);
        }
    }
    float4 b4 = *(const float4*)bia;
    float* outp = is_k ? (kout + c0) : (vout + (c0 - 128));
    #pragma unroll
    for (int i = 0; i < 16; ++i) {
        size_t row = (size_t)rowbase + 16 * rg + i;
        float4 o = { acc[i][0] + b4.x, acc[i][1] + b4.y, acc[i][2] + b4.z, acc[i][3] + b4.w };
        *(float4*)(outp + row * Dn) = o;
    }
}

// ---------------------------------------------------------------------------
// K2: q = LN(slots)@wq.T + bq ; also zero updates/norm accumulators.
// One block (64 threads) per (b,s) row.
__global__ __launch_bounds__(64) void k_qproj(
    const float* __restrict__ slots, const float* __restrict__ ns_g, const float* __restrict__ ns_b,
    const float* __restrict__ wq, const float* __restrict__ bq,
    float* __restrict__ qbuf, float* __restrict__ updates, float* __restrict__ norm)
{
    __shared__ float xn[128];
    const int t = threadIdx.x;
    const int bs = blockIdx.x;  // 0..511
    const float* row = slots + (size_t)bs * Dn;
    float2 x2 = ((const float2*)row)[t];
    float s  = x2.x + x2.y;
    float sq = x2.x*x2.x + x2.y*x2.y;
    #pragma unroll
    for (int m = 1; m <= 32; m <<= 1) { s += __shfl_xor(s, m); sq += __shfl_xor(sq, m); }
    float mu = s * (1.0f / 128.0f);
    float rs = rsqrtf(sq * (1.0f / 128.0f) - mu * mu + LN_EPS);
    xn[2*t]   = (x2.x - mu) * rs * ns_g[2*t]   + ns_b[2*t];
    xn[2*t+1] = (x2.y - mu) * rs * ns_g[2*t+1] + ns_b[2*t+1];
    __syncthreads();

    float a0 = 0.f, a1 = 0.f;
    const float* w0 = wq + (size_t)t * Dn;
    const float* w1 = wq + (size_t)(t + 64) * Dn;
    for (int d = 0; d < 128; d += 4) {
        float4 x4 = *(const float4*)&xn[d];
        a0 += dot4(x4, *(const float4*)(w0 + d));
        a1 += dot4(x4, *(const float4*)(w1 + d));
    }
    qbuf[(size_t)bs * Dn + t]      = a0 + bq[t];
    qbuf[(size_t)bs * Dn + t + 64] = a1 + bq[t + 64];

    // zero accumulators for this (b,s)
    float2 z = {0.f, 0.f};
    ((float2*)(updates + (size_t)bs * Dn))[t] = z;
    if (t == 0) norm[bs] = 0.f;
}

// ---------------------------------------------------------------------------
// K3: logits = k@q.T*scale -> softmax over S -> accumulate updates (unnormalized) + norms
// grid (16 chunks, 64 batches), 256 threads; 4 sub-tiles of 64 rows each.
__global__ __launch_bounds__(256) void k_attn(
    const float* __restrict__ kbuf, const float* __restrict__ vbuf,
    const float* __restrict__ qbuf, float* __restrict__ updates, float* __restrict__ norm)
{
    __shared__ float qs[8 * 128];    // 4 KiB
    __shared__ float ks[64 * 132];   // 33 KiB, stride 132: aligned b128, conflict-free
    __shared__ float vs[64 * 128];   // 32 KiB
    __shared__ float attn[64 * 9];   // logits then attn; stride 9 (odd) kills conflicts
    const int t = threadIdx.x;
    const int b = blockIdx.y;
    const int chunk = blockIdx.x;
    const float scale = 0.08838834764831845f;  // 1/sqrt(128)

    ((float4*)qs)[t] = ((const float4*)(qbuf + (size_t)b * Sn * Dn))[t];  // 256 float4 = 8x128

    const int r_l = t & 63;          // logits: row
    const int sg  = t >> 6;          // logits: slot pair (wave-uniform)
    const int d0  = (t & 31) * 4;    // updates: 4 d's
    const int su  = t >> 5;          // updates: slot (wave-half-uniform)
    float uacc[4] = {0.f, 0.f, 0.f, 0.f};
    float nacc[8] = {0.f,0.f,0.f,0.f,0.f,0.f,0.f,0.f};  // used by t<64

    for (int tile = 0; tile < 4; ++tile) {
        __syncthreads();  // protect previous tile's attn/vs (and q on tile 0)
        const size_t nbase = ((size_t)b * Nn) + chunk * 256 + tile * 64;
        const float* kg = kbuf + nbase * Dn;
        const float* vg = vbuf + nbase * Dn;
        #pragma unroll
        for (int it = 0; it < 8; ++it) {
            int f = it * 256 + t;      // 2048 float4s
            int r = f >> 5, c4 = f & 31;
            float4 kx = ((const float4*)kg)[f];
            *(float4*)&ks[r * 132 + c4 * 4] = kx;
            ((float4*)vs)[f] = ((const float4*)vg)[f];
        }
        __syncthreads();

        // logits: each thread 2 dots of length 128
        float a0 = 0.f, a1 = 0.f;
        const float* q0 = qs + (2 * sg) * 128;
        const float* q1 = qs + (2 * sg + 1) * 128;
        #pragma unroll 8
        for (int d = 0; d < 128; d += 4) {
            float4 k4 = *(const float4*)&ks[r_l * 132 + d];
            a0 += dot4(k4, *(const float4*)(q0 + d));
            a1 += dot4(k4, *(const float4*)(q1 + d));
        }
        attn[r_l * 9 + 2 * sg]     = a0 * scale;
        attn[r_l * 9 + 2 * sg + 1] = a1 * scale;
        __syncthreads();

        // softmax over S=8, first wave only (one thread per row)
        if (t < 64) {
            float l[8];
            float m = -1e30f;
            #pragma unroll
            for (int s2 = 0; s2 < 8; ++s2) { l[s2] = attn[t * 9 + s2]; m = fmaxf(m, l[s2]); }
            float sum = 0.f;
            #pragma unroll
            for (int s2 = 0; s2 < 8; ++s2) { l[s2] = __expf(l[s2] - m); sum += l[s2]; }
            float inv = 1.0f / sum;
            #pragma unroll
            for (int s2 = 0; s2 < 8; ++s2) {
                float p = l[s2] * inv;
                attn[t * 9 + s2] = p;
                nacc[s2] += p;
            }
        }
        __syncthreads();

        // updates partial: thread owns (slot su, d0..d0+3)
        #pragma unroll 8
        for (int r = 0; r < 64; ++r) {
            float a = attn[r * 9 + su];                      // broadcast
            float4 v4 = *(const float4*)&vs[r * 128 + d0];   // conflict-free b128
            uacc[0] += a * v4.x; uacc[1] += a * v4.y;
            uacc[2] += a * v4.z; uacc[3] += a * v4.w;
        }
    }

    float* up = updates + ((size_t)b * Sn + su) * Dn + d0;
    atomicAdd(up + 0, uacc[0]); atomicAdd(up + 1, uacc[1]);
    atomicAdd(up + 2, uacc[2]); atomicAdd(up + 3, uacc[3]);

    if (t < 64) {
        #pragma unroll
        for (int s2 = 0; s2 < 8; ++s2) {
            float v = nacc[s2];
            #pragma unroll
            for (int m = 1; m <= 32; m <<= 1) v += __shfl_xor(v, m);
            if (t == 0) atomicAdd(norm + b * Sn + s2, v);
        }
    }
}

// ---------------------------------------------------------------------------
// K4: updates /= clip(norm); GRU; LN; MLP(gelu); residual. One block (64 thr) per (b,s).
__global__ __launch_bounds__(64) void k_update(
    const float* __restrict__ slots, const float* __restrict__ updates, const float* __restrict__ norm,
    const float* __restrict__ wih, const float* __restrict__ whh,
    const float* __restrict__ bih, const float* __restrict__ bhh,
    const float* __restrict__ mlg, const float* __restrict__ mlb,
    const float* __restrict__ w1, const float* __restrict__ b1,
    const float* __restrict__ w2, const float* __restrict__ b2,
    float* __restrict__ outp)
{
    __shared__ float us[128];   // u, later hnew (residual)
    __shared__ float hs[128];
    __shared__ float lns[128];
    __shared__ float h1s[256];
    const int t = threadIdx.x;
    const int bs = blockIdx.x;

    float inv = 1.0f / fmaxf(norm[bs], 1e-8f);
    float2 u2 = ((const float2*)(updates + (size_t)bs * Dn))[t];
    float2 h2 = ((const float2*)(slots   + (size_t)bs * Dn))[t];
    u2.x *= inv; u2.y *= inv;
    ((float2*)us)[t] = u2;
    ((float2*)hs)[t] = h2;
    __syncthreads();

    // 12 dot products: gates (r,z,n) x elements (t, t+64) x (wih,whh)
    float gi[6] = {0,0,0,0,0,0}, gh[6] = {0,0,0,0,0,0};
    for (int d = 0; d < 128; d += 4) {
        float4 u4 = *(const float4*)&us[d];
        float4 h4 = *(const float4*)&hs[d];
        #pragma unroll
        for (int gate = 0; gate < 3; ++gate) {
            #pragma unroll
            for (int e = 0; e < 2; ++e) {
                int j = gate * 128 + t + e * 64;
                gi[gate*2+e] += dot4(u4, *(const float4*)(wih + (size_t)j * Dn + d));
                gh[gate*2+e] += dot4(h4, *(const float4*)(whh + (size_t)j * Dn + d));
            }
        }
    }
    __syncthreads();  // all reads of us done before overwrite

    float hnew[2];
    #pragma unroll
    for (int e = 0; e < 2; ++e) {
        int idx = t + e * 64;
        float ir = gi[0*2+e] + bih[idx],       hr = gh[0*2+e] + bhh[idx];
        float iz = gi[1*2+e] + bih[128+idx],   hz = gh[1*2+e] + bhh[128+idx];
        float in_= gi[2*2+e] + bih[256+idx],   hn = gh[2*2+e] + bhh[256+idx];
        float r = 1.0f / (1.0f + __expf(-(ir + hr)));
        float z = 1.0f / (1.0f + __expf(-(iz + hz)));
        float n = tanhf(in_ + r * hn);
        hnew[e] = (1.0f - z) * n + z * hs[idx];
    }
    // LN over hnew (each thread holds elements t and t+64)
    float s  = hnew[0] + hnew[1];
    float sq = hnew[0]*hnew[0] + hnew[1]*hnew[1];
    #pragma unroll
    for (int m = 1; m <= 32; m <<= 1) { s += __shfl_xor(s, m); sq += __shfl_xor(sq, m); }
    float mu = s * (1.0f / 128.0f);
    float rs = rsqrtf(sq * (1.0f / 128.0f) - mu * mu + LN_EPS);
    us[t]      = hnew[0];
    us[t + 64] = hnew[1];
    lns[t]      = (hnew[0] - mu) * rs * mlg[t]      + mlb[t];
    lns[t + 64] = (hnew[1] - mu) * rs * mlg[t + 64] + mlb[t + 64];
    __syncthreads();

    // fc1 (128 -> 256) + exact gelu
    float a[4] = {0,0,0,0};
    for (int d = 0; d < 128; d += 4) {
        float4 x4 = *(const float4*)&lns[d];
        #pragma unroll
        for (int c = 0; c < 4; ++c)
            a[c] += dot4(x4, *(const float4*)(w1 + (size_t)(t + c * 64) * Dn + d));
    }
    #pragma unroll
    for (int c = 0; c < 4; ++c) {
        float x = a[c] + b1[t + c * 64];
        h1s[t + c * 64] = 0.5f * x * (1.0f + erff(x * 0.70710678118654752f));
    }
    __syncthreads();

    // fc2 (256 -> 128) + residual
    float o0 = 0.f, o1 = 0.f;
    for (int d = 0; d < 256; d += 4) {
        float4 x4 = *(const float4*)&h1s[d];
        o0 += dot4(x4, *(const float4*)(w2 + (size_t)t * Hn + d));
        o1 += dot4(x4, *(const float4*)(w2 + (size_t)(t + 64) * Hn + d));
    }
    outp[(size_t)bs * Dn + t]      = us[t]      + o0 + b2[t];
    outp[(size_t)bs * Dn + t + 64] = us[t + 64] + o1 + b2[t + 64];
}

// ---------------------------------------------------------------------------
extern "C" void kernel_launch(void* const* d_in, const int* in_sizes, int n_in,
                              void* d_out, int out_size, void* d_ws, size_t ws_size,
                              hipStream_t stream) {
    (void)in_sizes; (void)n_in; (void)out_size; (void)ws_size;
    const float* inputs   = (const float*)d_in[0];
    const float* noise    = (const float*)d_in[1];
    const float* slots_mu = (const float*)d_in[2];
    const float* slots_ls = (const float*)d_in[3];
    const float* wq  = (const float*)d_in[4];
    const float* bq  = (const float*)d_in[5];
    const float* wk  = (const float*)d_in[6];
    const float* bk  = (const float*)d_in[7];
    const float* wv  = (const float*)d_in[8];
    const float* bv  = (const float*)d_in[9];
    const float* gwih = (const float*)d_in[10];
    const float* gwhh = (const float*)d_in[11];
    const float* gbih = (const float*)d_in[12];
    const float* gbhh = (const float*)d_in[13];
    const float* ns_g = (const float*)d_in[14];
    const float* ns_b = (const float*)d_in[15];
    const float* ni_g = (const float*)d_in[16];
    const float* ni_b = (const float*)d_in[17];
    const float* mlg  = (const float*)d_in[18];
    const float* mlb  = (const float*)d_in[19];
    const float* mw1  = (const float*)d_in[20];
    const float* mb1  = (const float*)d_in[21];
    const float* mw2  = (const float*)d_in[22];
    const float* mb2  = (const float*)d_in[23];

    float* ws      = (float*)d_ws;
    float* slots   = ws;                       // 65536
    float* qbuf    = ws + 65536;               // 65536
    float* updates = ws + 131072;              // 65536
    float* norm    = ws + 196608;              // 512
    float* kbuf    = ws + 262144;              // 33554432
    float* vbuf    = kbuf + (size_t)Bn * Nn * Dn;

    k_slots_init<<<4, 256, 0, stream>>>(slots_mu, slots_ls, noise, slots);
    k_lnkv<<<4096, 256, 0, stream>>>(inputs, ni_g, ni_b, wk, bk, wv, bv, kbuf, vbuf);
    for (int iter = 0; iter < 3; ++iter) {
        k_qproj<<<512, 64, 0, stream>>>(slots, ns_g, ns_b, wq, bq, qbuf, updates, norm);
        k_attn<<<dim3(16, 64), 256, 0, stream>>>(kbuf, vbuf, qbuf, updates, norm);
        float* outp = (iter == 2) ? (float*)d_out : slots;
        k_update<<<512, 64, 0, stream>>>(slots, updates, norm, gwih, gwhh, gbih, gbhh,
                                         mlg, mlb, mw1, mb1, mw2, mb2, outp);
    }
}

// Round 2
// 797.749 us; speedup vs baseline: 1.2549x; 1.2549x over previous
//
#include <hip/hip_runtime.h>
#include <hip/hip_bf16.h>
#include <math.h>

#define Bn 64
#define Nn 4096
#define Dn 128
#define Sn 8
#define Hn 256
#define LN_EPS 1e-5f
#define WL_S 136  // LDS row stride in bf16 elems: 272 B, 16B-aligned, 4-word bank shift/row

typedef __bf16 bf16x8 __attribute__((ext_vector_type(8)));
typedef float f32x4 __attribute__((ext_vector_type(4)));
typedef unsigned short ushort_t;

__device__ __forceinline__ float dot4(float4 a, float4 b) {
    return a.x*b.x + a.y*b.y + a.z*b.z + a.w*b.w;
}
__device__ __forceinline__ ushort_t f2bf(float f) {
    __bf16 b = (__bf16)f;  // fptrunc = RNE
    ushort_t u; __builtin_memcpy(&u, &b, 2); return u;
}
__device__ __forceinline__ float bflo(unsigned int u) {
    unsigned int x = u << 16; float f; __builtin_memcpy(&f, &x, 4); return f;
}
__device__ __forceinline__ float bfhi(unsigned int u) {
    unsigned int x = u & 0xFFFF0000u; float f; __builtin_memcpy(&f, &x, 4); return f;
}

// ---------------------------------------------------------------------------
// K0: slots = mu + exp(log_sigma) * noise, broadcast over batch
__global__ void k_slots_init(const float* __restrict__ mu, const float* __restrict__ ls,
                             const float* __restrict__ noise, float* __restrict__ slots) {
    int i = blockIdx.x * blockDim.x + threadIdx.x;
    if (i < Sn * Dn) {
        float v = mu[i] + __expf(ls[i]) * noise[i];
        #pragma unroll 4
        for (int b = 0; b < Bn; ++b) slots[b * Sn * Dn + i] = v;
    }
}

// ---------------------------------------------------------------------------
// Kw: pack [wk; wv] -> bf16 Wall[256][128]
__global__ void k_wprep(const float* __restrict__ wk, const float* __restrict__ wv,
                        ushort_t* __restrict__ wall) {
    int i = blockIdx.x * blockDim.x + threadIdx.x;  // 32768
    if (i < 32768) {
        float f = (i < 16384) ? wk[i] : wv[i - 16384];
        wall[i] = f2bf(f);
    }
}

// ---------------------------------------------------------------------------
// K1: LN + K/V projection via bf16 MFMA. Block = 512 thr (8 waves), 128 rows.
// Wave w: cols (w&3)*64..+63 (A = W-cols), rows (w>>2)*64..+63 (B = x-rows).
// D layout: col(lane&15)=x-row, row((lane>>4)*4+reg)=W-col -> lane holds 4
// consecutive output cols of one row: packed 8B (k, bf16) / 16B (v, fp32) stores.
__global__ __launch_bounds__(512) void k_lnkv_mfma(
    const float* __restrict__ inp, const float* __restrict__ ni_g, const float* __restrict__ ni_b,
    const ushort_t* __restrict__ wall, const float* __restrict__ bk, const float* __restrict__ bv,
    ushort_t* __restrict__ kout, float* __restrict__ vout)
{
    __shared__ ushort_t wl[256 * WL_S];  // 69632 B
    __shared__ ushort_t xs[128 * WL_S];  // 34816 B
    __shared__ float stats[256];
    __shared__ float gb[256];
    const int t = threadIdx.x;
    const int rowbase = blockIdx.x * 128;  // 2048 blocks

    if (t < 256) gb[t] = (t < 128) ? ni_g[t] : ni_b[t - 128];

    // stage W (bf16) -> LDS, 4096 uint4s
    #pragma unroll
    for (int it = 0; it < 8; ++it) {
        int f = it * 512 + t;
        int r = f >> 4, c8 = (f & 15) * 8;
        *(uint4*)&wl[r * WL_S + c8] = ((const uint4*)wall)[f];
    }

    // load inputs (held in regs), LN stats via 32-lane xor-reduce
    const float* src = inp + (size_t)rowbase * Dn;
    float4 xv[8];
    #pragma unroll
    for (int it = 0; it < 8; ++it) {
        int f = it * 512 + t;            // row = f>>5, 32 lanes/row
        float4 x4 = ((const float4*)src)[f];
        xv[it] = x4;
        float s  = x4.x + x4.y + x4.z + x4.w;
        float sq = x4.x*x4.x + x4.y*x4.y + x4.z*x4.z + x4.w*x4.w;
        #pragma unroll
        for (int m = 1; m <= 16; m <<= 1) { s += __shfl_xor(s, m); sq += __shfl_xor(sq, m); }
        if ((t & 31) == 0) {
            int r = it * 16 + (t >> 5);
            float mu  = s * (1.0f / 128.0f);
            float var = sq * (1.0f / 128.0f) - mu * mu;
            stats[2 * r]     = mu;
            stats[2 * r + 1] = rsqrtf(var + LN_EPS);
        }
    }
    __syncthreads();
    // normalize -> bf16 -> xs
    #pragma unroll
    for (int it = 0; it < 8; ++it) {
        int f = it * 512 + t;
        int r = f >> 5;
        int c = (f & 31) * 4;
        float mu = stats[2 * r], rs = stats[2 * r + 1];
        float4 x4 = xv[it];
        ushort_t o0 = f2bf((x4.x - mu) * rs * gb[c + 0] + gb[128 + c + 0]);
        ushort_t o1 = f2bf((x4.y - mu) * rs * gb[c + 1] + gb[128 + c + 1]);
        ushort_t o2 = f2bf((x4.z - mu) * rs * gb[c + 2] + gb[128 + c + 2]);
        ushort_t o3 = f2bf((x4.w - mu) * rs * gb[c + 3] + gb[128 + c + 3]);
        ushort4 o = {o0, o1, o2, o3};
        *(ushort4*)&xs[r * WL_S + c] = o;
    }
    __syncthreads();

    // MFMA
    const int lane = t & 63;
    const int w = t >> 6;
    const int colw  = (w & 3) * 64;   // W-col base for this wave
    const int rhalf = (w >> 2) * 64;  // x-row base
    const int l15 = lane & 15, q = lane >> 4;

    bf16x8 afr[4][4];
    #pragma unroll
    for (int ct = 0; ct < 4; ++ct)
        #pragma unroll
        for (int k = 0; k < 4; ++k)
            afr[ct][k] = *(const bf16x8*)&wl[(colw + ct * 16 + l15) * WL_S + k * 32 + q * 8];

    float4 bias[4];
    #pragma unroll
    for (int ct = 0; ct < 4; ++ct) {
        int c0 = colw + ct * 16 + q * 4;
        bias[ct] = (colw < 128) ? *(const float4*)&bk[c0] : *(const float4*)&bv[c0 - 128];
    }

    #pragma unroll
    for (int rt = 0; rt < 4; ++rt) {
        bf16x8 bfr[4];
        #pragma unroll
        for (int k = 0; k < 4; ++k)
            bfr[k] = *(const bf16x8*)&xs[(rhalf + rt * 16 + l15) * WL_S + k * 32 + q * 8];
        size_t grow = (size_t)rowbase + rhalf + rt * 16 + l15;
        #pragma unroll
        for (int ct = 0; ct < 4; ++ct) {
            f32x4 acc = {0.f, 0.f, 0.f, 0.f};
            #pragma unroll
            for (int k = 0; k < 4; ++k)
                acc = __builtin_amdgcn_mfma_f32_16x16x32_bf16(afr[ct][k], bfr[k], acc, 0, 0, 0);
            int c0 = colw + ct * 16 + q * 4;
            if (colw < 128) {
                ushort4 o = { f2bf(acc[0] + bias[ct].x), f2bf(acc[1] + bias[ct].y),
                              f2bf(acc[2] + bias[ct].z), f2bf(acc[3] + bias[ct].w) };
                *(ushort4*)&kout[grow * Dn + c0] = o;
            } else {
                float4 o = { acc[0] + bias[ct].x, acc[1] + bias[ct].y,
                             acc[2] + bias[ct].z, acc[3] + bias[ct].w };
                *(float4*)&vout[grow * Dn + (c0 - 128)] = o;
            }
        }
    }
}

// ---------------------------------------------------------------------------
// K2: q = LN(slots)@wq.T + bq ; zero updates/norm. One 64-thr block per (b,s).
__global__ __launch_bounds__(64) void k_qproj(
    const float* __restrict__ slots, const float* __restrict__ ns_g, const float* __restrict__ ns_b,
    const float* __restrict__ wq, const float* __restrict__ bq,
    float* __restrict__ qbuf, float* __restrict__ updates, float* __restrict__ norm)
{
    __shared__ float xn[128];
    const int t = threadIdx.x;
    const int bs = blockIdx.x;
    const float* row = slots + (size_t)bs * Dn;
    float2 x2 = ((const float2*)row)[t];
    float s  = x2.x + x2.y;
    float sq = x2.x*x2.x + x2.y*x2.y;
    #pragma unroll
    for (int m = 1; m <= 32; m <<= 1) { s += __shfl_xor(s, m); sq += __shfl_xor(sq, m); }
    float mu = s * (1.0f / 128.0f);
    float rs = rsqrtf(sq * (1.0f / 128.0f) - mu * mu + LN_EPS);
    xn[2*t]   = (x2.x - mu) * rs * ns_g[2*t]   + ns_b[2*t];
    xn[2*t+1] = (x2.y - mu) * rs * ns_g[2*t+1] + ns_b[2*t+1];
    __syncthreads();

    float a0 = 0.f, a1 = 0.f;
    const float* w0 = wq + (size_t)t * Dn;
    const float* w1 = wq + (size_t)(t + 64) * Dn;
    for (int d = 0; d < 128; d += 4) {
        float4 x4 = *(const float4*)&xn[d];
        a0 += dot4(x4, *(const float4*)(w0 + d));
        a1 += dot4(x4, *(const float4*)(w1 + d));
    }
    qbuf[(size_t)bs * Dn + t]      = a0 + bq[t];
    qbuf[(size_t)bs * Dn + t + 64] = a1 + bq[t + 64];

    float2 z = {0.f, 0.f};
    ((float2*)(updates + (size_t)bs * Dn))[t] = z;
    if (t == 0) norm[bs] = 0.f;
}

// ---------------------------------------------------------------------------
// K3: logits -> softmax(S=8) -> unnormalized updates + norms. k bf16, v fp32.
// grid (32 chunks, 64 batches), 256 thr, 2 tiles of 64 rows.
__global__ __launch_bounds__(256) void k_attn(
    const ushort_t* __restrict__ kbuf, const float* __restrict__ vbuf,
    const float* __restrict__ qbuf, float* __restrict__ updates, float* __restrict__ norm)
{
    __shared__ float qs[8 * 128];
    __shared__ ushort_t ks[64 * WL_S];  // bf16, 4-word/row bank shift -> b128 floor
    __shared__ float vs[64 * 128];
    __shared__ float attn[64 * 9];
    const int t = threadIdx.x;
    const int b = blockIdx.y;
    const int chunk = blockIdx.x;
    const float scale = 0.08838834764831845f;

    ((float4*)qs)[t] = ((const float4*)(qbuf + (size_t)b * Sn * Dn))[t];

    const int r_l = t & 63;
    const int sg  = t >> 6;
    const int d0  = (t & 31) * 4;
    const int su  = t >> 5;
    float uacc[4] = {0.f, 0.f, 0.f, 0.f};
    float nacc[8] = {0.f,0.f,0.f,0.f,0.f,0.f,0.f,0.f};

    for (int tile = 0; tile < 2; ++tile) {
        __syncthreads();
        const size_t nbase = ((size_t)b * Nn) + chunk * 128 + tile * 64;
        const ushort_t* kg = kbuf + nbase * Dn;
        const float* vg = vbuf + nbase * Dn;
        #pragma unroll
        for (int it = 0; it < 4; ++it) {      // k: 1024 uint4s
            int f = it * 256 + t;
            int r = f >> 4, c8 = (f & 15) * 8;
            *(uint4*)&ks[r * WL_S + c8] = ((const uint4*)kg)[f];
        }
        #pragma unroll
        for (int it = 0; it < 8; ++it) {      // v: 2048 float4s
            int f = it * 256 + t;
            ((float4*)vs)[f] = ((const float4*)vg)[f];
        }
        __syncthreads();

        // logits: 2 dots of 128 per thread, bf16 k unpacked inline
        float a0 = 0.f, a1 = 0.f;
        const ushort_t* krow = &ks[r_l * WL_S];
        const float* q0 = qs + (2 * sg) * 128;
        const float* q1 = q0 + 128;
        #pragma unroll 4
        for (int d = 0; d < 128; d += 8) {
            uint4 kk = *(const uint4*)(krow + d);
            float k0 = bflo(kk.x), k1 = bfhi(kk.x);
            float k2 = bflo(kk.y), k3 = bfhi(kk.y);
            float k4 = bflo(kk.z), k5 = bfhi(kk.z);
            float k6 = bflo(kk.w), k7 = bfhi(kk.w);
            float4 qa = *(const float4*)(q0 + d);
            float4 qb = *(const float4*)(q0 + d + 4);
            a0 += k0*qa.x + k1*qa.y + k2*qa.z + k3*qa.w
                + k4*qb.x + k5*qb.y + k6*qb.z + k7*qb.w;
            float4 qc = *(const float4*)(q1 + d);
            float4 qd = *(const float4*)(q1 + d + 4);
            a1 += k0*qc.x + k1*qc.y + k2*qc.z + k3*qc.w
                + k4*qd.x + k5*qd.y + k6*qd.z + k7*qd.w;
        }
        attn[r_l * 9 + 2 * sg]     = a0 * scale;
        attn[r_l * 9 + 2 * sg + 1] = a1 * scale;
        __syncthreads();

        if (t < 64) {
            float l[8];
            float m = -1e30f;
            #pragma unroll
            for (int s2 = 0; s2 < 8; ++s2) { l[s2] = attn[t * 9 + s2]; m = fmaxf(m, l[s2]); }
            float sum = 0.f;
            #pragma unroll
            for (int s2 = 0; s2 < 8; ++s2) { l[s2] = __expf(l[s2] - m); sum += l[s2]; }
            float inv = 1.0f / sum;
            #pragma unroll
            for (int s2 = 0; s2 < 8; ++s2) {
                float p = l[s2] * inv;
                attn[t * 9 + s2] = p;
                nacc[s2] += p;
            }
        }
        __syncthreads();

        #pragma unroll 8
        for (int r = 0; r < 64; ++r) {
            float a = attn[r * 9 + su];
            float4 v4 = *(const float4*)&vs[r * 128 + d0];
            uacc[0] += a * v4.x; uacc[1] += a * v4.y;
            uacc[2] += a * v4.z; uacc[3] += a * v4.w;
        }
    }

    float* up = updates + ((size_t)b * Sn + su) * Dn + d0;
    atomicAdd(up + 0, uacc[0]); atomicAdd(up + 1, uacc[1]);
    atomicAdd(up + 2, uacc[2]); atomicAdd(up + 3, uacc[3]);

    if (t < 64) {
        #pragma unroll
        for (int s2 = 0; s2 < 8; ++s2) {
            float v = nacc[s2];
            #pragma unroll
            for (int m = 1; m <= 32; m <<= 1) v += __shfl_xor(v, m);
            if (t == 0) atomicAdd(norm + b * Sn + s2, v);
        }
    }
}

// ---------------------------------------------------------------------------
// K4: updates /= clip(norm); GRU; LN; MLP(gelu); residual. 64-thr block per (b,s).
__global__ __launch_bounds__(64) void k_update(
    const float* __restrict__ slots, const float* __restrict__ updates, const float* __restrict__ norm,
    const float* __restrict__ wih, const float* __restrict__ whh,
    const float* __restrict__ bih, const float* __restrict__ bhh,
    const float* __restrict__ mlg, const float* __restrict__ mlb,
    const float* __restrict__ w1, const float* __restrict__ b1,
    const float* __restrict__ w2, const float* __restrict__ b2,
    float* __restrict__ outp)
{
    __shared__ float us[128];
    __shared__ float hs[128];
    __shared__ float lns[128];
    __shared__ float h1s[256];
    const int t = threadIdx.x;
    const int bs = blockIdx.x;

    float inv = 1.0f / fmaxf(norm[bs], 1e-8f);
    float2 u2 = ((const float2*)(updates + (size_t)bs * Dn))[t];
    float2 h2 = ((const float2*)(slots   + (size_t)bs * Dn))[t];
    u2.x *= inv; u2.y *= inv;
    ((float2*)us)[t] = u2;
    ((float2*)hs)[t] = h2;
    __syncthreads();

    float gi[6] = {0,0,0,0,0,0}, gh[6] = {0,0,0,0,0,0};
    for (int d = 0; d < 128; d += 4) {
        float4 u4 = *(const float4*)&us[d];
        float4 h4 = *(const float4*)&hs[d];
        #pragma unroll
        for (int gate = 0; gate < 3; ++gate) {
            #pragma unroll
            for (int e = 0; e < 2; ++e) {
                int j = gate * 128 + t + e * 64;
                gi[gate*2+e] += dot4(u4, *(const float4*)(wih + (size_t)j * Dn + d));
                gh[gate*2+e] += dot4(h4, *(const float4*)(whh + (size_t)j * Dn + d));
            }
        }
    }
    __syncthreads();

    float hnew[2];
    #pragma unroll
    for (int e = 0; e < 2; ++e) {
        int idx = t + e * 64;
        float ir = gi[0*2+e] + bih[idx],       hr = gh[0*2+e] + bhh[idx];
        float iz = gi[1*2+e] + bih[128+idx],   hz = gh[1*2+e] + bhh[128+idx];
        float in_= gi[2*2+e] + bih[256+idx],   hn = gh[2*2+e] + bhh[256+idx];
        float r = 1.0f / (1.0f + __expf(-(ir + hr)));
        float z = 1.0f / (1.0f + __expf(-(iz + hz)));
        float n = tanhf(in_ + r * hn);
        hnew[e] = (1.0f - z) * n + z * hs[idx];
    }
    float s  = hnew[0] + hnew[1];
    float sq = hnew[0]*hnew[0] + hnew[1]*hnew[1];
    #pragma unroll
    for (int m = 1; m <= 32; m <<= 1) { s += __shfl_xor(s, m); sq += __shfl_xor(sq, m); }
    float mu = s * (1.0f / 128.0f);
    float rs = rsqrtf(sq * (1.0f / 128.0f) - mu * mu + LN_EPS);
    us[t]      = hnew[0];
    us[t + 64] = hnew[1];
    lns[t]      = (hnew[0] - mu) * rs * mlg[t]      + mlb[t];
    lns[t + 64] = (hnew[1] - mu) * rs * mlg[t + 64] + mlb[t + 64];
    __syncthreads();

    float a[4] = {0,0,0,0};
    for (int d = 0; d < 128; d += 4) {
        float4 x4 = *(const float4*)&lns[d];
        #pragma unroll
        for (int c = 0; c < 4; ++c)
            a[c] += dot4(x4, *(const float4*)(w1 + (size_t)(t + c * 64) * Dn + d));
    }
    #pragma unroll
    for (int c = 0; c < 4; ++c) {
        float x = a[c] + b1[t + c * 64];
        h1s[t + c * 64] = 0.5f * x * (1.0f + erff(x * 0.70710678118654752f));
    }
    __syncthreads();

    float o0 = 0.f, o1 = 0.f;
    for (int d = 0; d < 256; d += 4) {
        float4 x4 = *(const float4*)&h1s[d];
        o0 += dot4(x4, *(const float4*)(w2 + (size_t)t * Hn + d));
        o1 += dot4(x4, *(const float4*)(w2 + (size_t)(t + 64) * Hn + d));
    }
    outp[(size_t)bs * Dn + t]      = us[t]      + o0 + b2[t];
    outp[(size_t)bs * Dn + t + 64] = us[t + 64] + o1 + b2[t + 64];
}

// ---------------------------------------------------------------------------
extern "C" void kernel_launch(void* const* d_in, const int* in_sizes, int n_in,
                              void* d_out, int out_size, void* d_ws, size_t ws_size,
                              hipStream_t stream) {
    (void)in_sizes; (void)n_in; (void)out_size; (void)ws_size;
    const float* inputs   = (const float*)d_in[0];
    const float* noise    = (const float*)d_in[1];
    const float* slots_mu = (const float*)d_in[2];
    const float* slots_ls = (const float*)d_in[3];
    const float* wq  = (const float*)d_in[4];
    const float* bq  = (const float*)d_in[5];
    const float* wk  = (const float*)d_in[6];
    const float* bk  = (const float*)d_in[7];
    const float* wv  = (const float*)d_in[8];
    const float* bv  = (const float*)d_in[9];
    const float* gwih = (const float*)d_in[10];
    const float* gwhh = (const float*)d_in[11];
    const float* gbih = (const float*)d_in[12];
    const float* gbhh = (const float*)d_in[13];
    const float* ns_g = (const float*)d_in[14];
    const float* ns_b = (const float*)d_in[15];
    const float* ni_g = (const float*)d_in[16];
    const float* ni_b = (const float*)d_in[17];
    const float* mlg  = (const float*)d_in[18];
    const float* mlb  = (const float*)d_in[19];
    const float* mw1  = (const float*)d_in[20];
    const float* mb1  = (const float*)d_in[21];
    const float* mw2  = (const float*)d_in[22];
    const float* mb2  = (const float*)d_in[23];

    float* ws      = (float*)d_ws;
    float* slots   = ws;                       // 65536 f
    float* qbuf    = ws + 65536;               // 65536 f
    float* updates = ws + 131072;              // 65536 f
    float* norm    = ws + 196608;              // 512 f
    ushort_t* wall = (ushort_t*)(ws + 197120); // 32768 bf16 (16384 f)
    ushort_t* kbuf = (ushort_t*)(ws + 262144); // 33554432 bf16 (16777216 f)
    float* vbuf    = ws + 262144 + 16777216;   // 33554432 f

    k_slots_init<<<4, 256, 0, stream>>>(slots_mu, slots_ls, noise, slots);
    k_wprep<<<128, 256, 0, stream>>>(wk, wv, wall);
    k_lnkv_mfma<<<2048, 512, 0, stream>>>(inputs, ni_g, ni_b, wall, bk, bv, kbuf, vbuf);
    for (int iter = 0; iter < 3; ++iter) {
        k_qproj<<<512, 64, 0, stream>>>(slots, ns_g, ns_b, wq, bq, qbuf, updates, norm);
        k_attn<<<dim3(32, 64), 256, 0, stream>>>(kbuf, vbuf, qbuf, updates, norm);
        float* outp = (iter == 2) ? (float*)d_out : slots;
        k_update<<<512, 64, 0, stream>>>(slots, updates, norm, gwih, gwhh, gbih, gbhh,
                                         mlg, mlb, mw1, mb1, mw2, mb2, outp);
    }
}

// Round 3
// 613.437 us; speedup vs baseline: 1.6319x; 1.3005x over previous
//
#include <hip/hip_runtime.h>
#include <hip/hip_bf16.h>
#include <math.h>

#define Bn 64
#define Nn 4096
#define Dn 128
#define Sn 8
#define Hn 256
#define LN_EPS 1e-5f
#define KS_S 136  // LDS row stride (bf16 elems) for k/v/x tiles: 272B, 16B-aligned

typedef __bf16 bf16x8 __attribute__((ext_vector_type(8)));
typedef float f32x4 __attribute__((ext_vector_type(4)));
typedef unsigned short ushort_t;

__device__ __forceinline__ float dot4(float4 a, float4 b) {
    return a.x*b.x + a.y*b.y + a.z*b.z + a.w*b.w;
}
__device__ __forceinline__ ushort_t f2bf(float f) {
    __bf16 b = (__bf16)f;
    ushort_t u; __builtin_memcpy(&u, &b, 2); return u;
}
__device__ __forceinline__ float bflo(unsigned int u) {
    unsigned int x = u << 16; float f; __builtin_memcpy(&f, &x, 4); return f;
}
__device__ __forceinline__ float bfhi(unsigned int u) {
    unsigned int x = u & 0xFFFF0000u; float f; __builtin_memcpy(&f, &x, 4); return f;
}

// ---------------------------------------------------------------------------
// K0: slots = mu + exp(log_sigma) * noise, broadcast over batch
__global__ void k_slots_init(const float* __restrict__ mu, const float* __restrict__ ls,
                             const float* __restrict__ noise, float* __restrict__ slots) {
    int i = blockIdx.x * blockDim.x + threadIdx.x;
    if (i < Sn * Dn) {
        float v = mu[i] + __expf(ls[i]) * noise[i];
        #pragma unroll 4
        for (int b = 0; b < Bn; ++b) slots[b * Sn * Dn + i] = v;
    }
}

// ---------------------------------------------------------------------------
// Kw: pack [wk; wv] -> bf16 in MFMA A-fragment order so lnkv's frag loads are
// coalesced: chunk ((G*4+k)*64 + q*16 + l) holds row G*16+l, cols k*32+q*8..+7
__global__ void k_wprep(const float* __restrict__ wk, const float* __restrict__ wv,
                        ushort_t* __restrict__ wallT) {
    int o = blockIdx.x * blockDim.x + threadIdx.x;  // 32768 bf16 outputs
    if (o < 32768) {
        int e = o & 7;
        int l = (o >> 3) & 15;
        int q = (o >> 7) & 3;
        int k = (o >> 9) & 3;
        int G = o >> 11;                 // 0..15
        int row = G * 16 + l;            // 0..255 (k cols then v cols)
        int col = k * 32 + q * 8 + e;    // 0..127
        float f = (row < 128) ? wk[row * 128 + col] : wv[(row - 128) * 128 + col];
        wallT[o] = f2bf(f);
    }
}

// ---------------------------------------------------------------------------
// K1: LN + K/V projection via bf16 MFMA. 256 thr (4 waves), 64 rows/block.
// Wave w handles W-cols w*64..+63 (A operand, frags direct from global wallT),
// all 64 x-rows (B operand from LDS). Outputs k and v both bf16.
__global__ __launch_bounds__(256) void k_lnkv_mfma(
    const float* __restrict__ inp, const float* __restrict__ ni_g, const float* __restrict__ ni_b,
    const ushort_t* __restrict__ wallT, const float* __restrict__ bk, const float* __restrict__ bv,
    ushort_t* __restrict__ kout, ushort_t* __restrict__ vout)
{
    __shared__ ushort_t xs[64 * KS_S];   // 17408 B
    __shared__ float stats[128];
    __shared__ float gb[256];
    const int t = threadIdx.x;
    const int rowbase = blockIdx.x * 64;  // 4096 blocks

    gb[t] = (t < 128) ? ni_g[t] : ni_b[t - 128];

    // load inputs (regs) + LN stats (32 lanes per row)
    const float* src = inp + (size_t)rowbase * Dn;
    float4 xv[8];
    #pragma unroll
    for (int it = 0; it < 8; ++it) {
        int f = it * 256 + t;
        float4 x4 = ((const float4*)src)[f];
        xv[it] = x4;
        float s  = x4.x + x4.y + x4.z + x4.w;
        float sq = x4.x*x4.x + x4.y*x4.y + x4.z*x4.z + x4.w*x4.w;
        #pragma unroll
        for (int m = 1; m <= 16; m <<= 1) { s += __shfl_xor(s, m); sq += __shfl_xor(sq, m); }
        if ((t & 31) == 0) {
            int r = it * 8 + (t >> 5);
            float mu  = s * (1.0f / 128.0f);
            float var = sq * (1.0f / 128.0f) - mu * mu;
            stats[2 * r]     = mu;
            stats[2 * r + 1] = rsqrtf(var + LN_EPS);
        }
    }
    __syncthreads();
    #pragma unroll
    for (int it = 0; it < 8; ++it) {
        int f = it * 256 + t;
        int r = f >> 5;
        int c = (f & 31) * 4;
        float mu = stats[2 * r], rs = stats[2 * r + 1];
        float4 x4 = xv[it];
        ushort4 o = { f2bf((x4.x - mu) * rs * gb[c + 0] + gb[128 + c + 0]),
                      f2bf((x4.y - mu) * rs * gb[c + 1] + gb[128 + c + 1]),
                      f2bf((x4.z - mu) * rs * gb[c + 2] + gb[128 + c + 2]),
                      f2bf((x4.w - mu) * rs * gb[c + 3] + gb[128 + c + 3]) };
        *(ushort4*)&xs[r * KS_S + c] = o;
    }
    __syncthreads();

    const int lane = t & 63;
    const int w = t >> 6;
    const int colw = w * 64;             // 0,64 -> k ; 128,192 -> v
    const int l15 = lane & 15, q = lane >> 4;

    // A fragments: coalesced 16B loads from fragment-ordered wallT (L2-hot)
    bf16x8 afr[4][4];
    #pragma unroll
    for (int ct = 0; ct < 4; ++ct) {
        int G = w * 4 + ct;
        #pragma unroll
        for (int k = 0; k < 4; ++k)
            afr[ct][k] = *(const bf16x8*)&wallT[(size_t)((G * 4 + k) * 64 + lane) * 8];
    }
    float4 bias[4];
    #pragma unroll
    for (int ct = 0; ct < 4; ++ct) {
        int c0 = colw + ct * 16 + q * 4;
        bias[ct] = (colw < 128) ? *(const float4*)&bk[c0] : *(const float4*)&bv[c0 - 128];
    }

    #pragma unroll
    for (int rt = 0; rt < 4; ++rt) {
        bf16x8 bfr[4];
        #pragma unroll
        for (int k = 0; k < 4; ++k)
            bfr[k] = *(const bf16x8*)&xs[(rt * 16 + l15) * KS_S + k * 32 + q * 8];
        size_t grow = (size_t)rowbase + rt * 16 + l15;
        #pragma unroll
        for (int ct = 0; ct < 4; ++ct) {
            f32x4 acc = {0.f, 0.f, 0.f, 0.f};
            #pragma unroll
            for (int k = 0; k < 4; ++k)
                acc = __builtin_amdgcn_mfma_f32_16x16x32_bf16(afr[ct][k], bfr[k], acc, 0, 0, 0);
            int c0 = colw + ct * 16 + q * 4;
            ushort4 o = { f2bf(acc[0] + bias[ct].x), f2bf(acc[1] + bias[ct].y),
                          f2bf(acc[2] + bias[ct].z), f2bf(acc[3] + bias[ct].w) };
            if (colw < 128) *(ushort4*)&kout[grow * Dn + c0] = o;
            else            *(ushort4*)&vout[grow * Dn + (c0 - 128)] = o;
        }
    }
}

// ---------------------------------------------------------------------------
// K2: q = LN(slots)@wq.T + bq for 8 rows/block (64 blocks x 256 thr);
// also zeroes updates/norm accumulators.
__global__ __launch_bounds__(256) void k_qproj2(
    const float* __restrict__ slots, const float* __restrict__ ns_g, const float* __restrict__ ns_b,
    const float* __restrict__ wq, const float* __restrict__ bq,
    float* __restrict__ qbuf, float* __restrict__ updates, float* __restrict__ norm)
{
    __shared__ float lnq[8][128];
    const int t = threadIdx.x;
    const int bs0 = blockIdx.x * 8;
    {
        int r = t >> 5, c = (t & 31) * 4;
        float4 x4 = *(const float4*)&slots[(size_t)(bs0 + r) * Dn + c];
        float s  = x4.x + x4.y + x4.z + x4.w;
        float sq = x4.x*x4.x + x4.y*x4.y + x4.z*x4.z + x4.w*x4.w;
        #pragma unroll
        for (int m = 1; m <= 16; m <<= 1) { s += __shfl_xor(s, m); sq += __shfl_xor(sq, m); }
        float mu = s * (1.0f / 128.0f);
        float rs = rsqrtf(sq * (1.0f / 128.0f) - mu * mu + LN_EPS);
        lnq[r][c+0] = (x4.x - mu) * rs * ns_g[c+0] + ns_b[c+0];
        lnq[r][c+1] = (x4.y - mu) * rs * ns_g[c+1] + ns_b[c+1];
        lnq[r][c+2] = (x4.z - mu) * rs * ns_g[c+2] + ns_b[c+2];
        lnq[r][c+3] = (x4.w - mu) * rs * ns_g[c+3] + ns_b[c+3];
    }
    __syncthreads();
    {
        int c = t & 127, rb = (t >> 7) * 4;
        const float* W = wq + (size_t)c * Dn;
        float acc[4] = {0.f, 0.f, 0.f, 0.f};
        for (int d = 0; d < 128; d += 4) {
            float4 w4 = *(const float4*)(W + d);
            #pragma unroll
            for (int rr = 0; rr < 4; ++rr) acc[rr] += dot4(w4, *(const float4*)&lnq[rb + rr][d]);
        }
        float bb = bq[c];
        #pragma unroll
        for (int rr = 0; rr < 4; ++rr)
            qbuf[(size_t)(bs0 + rb + rr) * Dn + c] = acc[rr] + bb;
    }
    float4 z = {0.f, 0.f, 0.f, 0.f};
    *(float4*)&updates[(size_t)bs0 * Dn + t * 4] = z;
    if (t < 8) norm[bs0 + t] = 0.f;
}

// ---------------------------------------------------------------------------
// K3: logits -> softmax(S=8) -> unnormalized updates + norms. k,v bf16.
__global__ __launch_bounds__(256) void k_attn(
    const ushort_t* __restrict__ kbuf, const ushort_t* __restrict__ vbuf,
    const float* __restrict__ qbuf, float* __restrict__ updates, float* __restrict__ norm)
{
    __shared__ float qs[8 * 128];
    __shared__ ushort_t ks[64 * KS_S];
    __shared__ ushort_t vs[64 * KS_S];
    __shared__ float attn[64 * 9];
    const int t = threadIdx.x;
    const int b = blockIdx.y;
    const int chunk = blockIdx.x;
    const float scale = 0.08838834764831845f;

    ((float4*)qs)[t] = ((const float4*)(qbuf + (size_t)b * Sn * Dn))[t];

    const int r_l = t & 63;
    const int sg  = t >> 6;
    const int d0  = (t & 31) * 4;
    const int su  = t >> 5;
    float uacc[4] = {0.f, 0.f, 0.f, 0.f};
    float nacc[8] = {0.f,0.f,0.f,0.f,0.f,0.f,0.f,0.f};

    for (int tile = 0; tile < 2; ++tile) {
        __syncthreads();
        const size_t nbase = ((size_t)b * Nn) + chunk * 128 + tile * 64;
        const ushort_t* kg = kbuf + nbase * Dn;
        const ushort_t* vg = vbuf + nbase * Dn;
        #pragma unroll
        for (int it = 0; it < 4; ++it) {
            int f = it * 256 + t;
            int r = f >> 4, c8 = (f & 15) * 8;
            *(uint4*)&ks[r * KS_S + c8] = ((const uint4*)kg)[f];
            *(uint4*)&vs[r * KS_S + c8] = ((const uint4*)vg)[f];
        }
        __syncthreads();

        float a0 = 0.f, a1 = 0.f;
        const ushort_t* krow = &ks[r_l * KS_S];
        const float* q0 = qs + (2 * sg) * 128;
        const float* q1 = q0 + 128;
        #pragma unroll 4
        for (int d = 0; d < 128; d += 8) {
            uint4 kk = *(const uint4*)(krow + d);
            float k0 = bflo(kk.x), k1 = bfhi(kk.x);
            float k2 = bflo(kk.y), k3 = bfhi(kk.y);
            float k4 = bflo(kk.z), k5 = bfhi(kk.z);
            float k6 = bflo(kk.w), k7 = bfhi(kk.w);
            float4 qa = *(const float4*)(q0 + d);
            float4 qb = *(const float4*)(q0 + d + 4);
            a0 += k0*qa.x + k1*qa.y + k2*qa.z + k3*qa.w
                + k4*qb.x + k5*qb.y + k6*qb.z + k7*qb.w;
            float4 qc = *(const float4*)(q1 + d);
            float4 qd = *(const float4*)(q1 + d + 4);
            a1 += k0*qc.x + k1*qc.y + k2*qc.z + k3*qc.w
                + k4*qd.x + k5*qd.y + k6*qd.z + k7*qd.w;
        }
        attn[r_l * 9 + 2 * sg]     = a0 * scale;
        attn[r_l * 9 + 2 * sg + 1] = a1 * scale;
        __syncthreads();

        if (t < 64) {
            float l[8];
            float m = -1e30f;
            #pragma unroll
            for (int s2 = 0; s2 < 8; ++s2) { l[s2] = attn[t * 9 + s2]; m = fmaxf(m, l[s2]); }
            float sum = 0.f;
            #pragma unroll
            for (int s2 = 0; s2 < 8; ++s2) { l[s2] = __expf(l[s2] - m); sum += l[s2]; }
            float inv = 1.0f / sum;
            #pragma unroll
            for (int s2 = 0; s2 < 8; ++s2) {
                float p = l[s2] * inv;
                attn[t * 9 + s2] = p;
                nacc[s2] += p;
            }
        }
        __syncthreads();

        #pragma unroll 8
        for (int r = 0; r < 64; ++r) {
            float a = attn[r * 9 + su];
            uint2 vv = *(const uint2*)&vs[r * KS_S + d0];
            uacc[0] += a * bflo(vv.x); uacc[1] += a * bfhi(vv.x);
            uacc[2] += a * bflo(vv.y); uacc[3] += a * bfhi(vv.y);
        }
    }

    float* up = updates + ((size_t)b * Sn + su) * Dn + d0;
    atomicAdd(up + 0, uacc[0]); atomicAdd(up + 1, uacc[1]);
    atomicAdd(up + 2, uacc[2]); atomicAdd(up + 3, uacc[3]);

    if (t < 64) {
        #pragma unroll
        for (int s2 = 0; s2 < 8; ++s2) {
            float v = nacc[s2];
            #pragma unroll
            for (int m = 1; m <= 32; m <<= 1) v += __shfl_xor(v, m);
            if (t == 0) atomicAdd(norm + b * Sn + s2, v);
        }
    }
}

// ---------------------------------------------------------------------------
// K4: GRU + LN + MLP + residual for 8 rows/block (64 blocks x 256 thr).
// Weight rows loaded once, dotted against all 8 activation rows.
// If do_q: also computes next iteration's q and zeroes accumulators.
__global__ __launch_bounds__(256) void k_update2(
    const float* __restrict__ slots, const float* __restrict__ updates_in,
    const float* __restrict__ norm,
    const float* __restrict__ wih, const float* __restrict__ whh,
    const float* __restrict__ bih, const float* __restrict__ bhh,
    const float* __restrict__ mlg, const float* __restrict__ mlb,
    const float* __restrict__ w1, const float* __restrict__ b1,
    const float* __restrict__ w2, const float* __restrict__ b2,
    const float* __restrict__ ns_g, const float* __restrict__ ns_b,
    const float* __restrict__ wq, const float* __restrict__ bq,
    float* __restrict__ outp, float* __restrict__ qbuf,
    float* __restrict__ upd_zero, float* __restrict__ norm_zero, int do_q)
{
    __shared__ float us[8][128];     // u, then hnew
    __shared__ float hs[8][128];
    __shared__ float gs[768 * 9];    // gate pre-activations, stride 9
    __shared__ float lns[8][128];    // LN'd hnew; reused as LN'd snew for q
    __shared__ float h1s[8 * 260];
    __shared__ float sn[8 * 132];
    const int t = threadIdx.x;
    const int bs0 = blockIdx.x * 8;

    // phase 1: load u (scaled by 1/norm) and h
    {
        int r = t >> 5, c = (t & 31) * 4;
        float inv = 1.0f / fmaxf(norm[bs0 + r], 1e-8f);
        float4 u4 = *(const float4*)&updates_in[(size_t)(bs0 + r) * Dn + c];
        float4 h4 = *(const float4*)&slots[(size_t)(bs0 + r) * Dn + c];
        u4.x *= inv; u4.y *= inv; u4.z *= inv; u4.w *= inv;
        *(float4*)&us[r][c] = u4;
        *(float4*)&hs[r][c] = h4;
    }
    __syncthreads();

    // phase 2: 768 virtual weight rows ([wih;whh]), 3 per thread, 8 dots each
    #pragma unroll
    for (int jj = 0; jj < 3; ++jj) {
        int j = t + jj * 256;
        const float* W = (j < 384) ? (wih + (size_t)j * Dn) : (whh + (size_t)(j - 384) * Dn);
        const float* X = (j < 384) ? &us[0][0] : &hs[0][0];
        float acc[8] = {0.f,0.f,0.f,0.f,0.f,0.f,0.f,0.f};
        for (int d = 0; d < 128; d += 4) {
            float4 w4 = *(const float4*)(W + d);
            #pragma unroll
            for (int r = 0; r < 8; ++r)
                acc[r] += dot4(w4, *(const float4*)(X + r * 128 + d));
        }
        #pragma unroll
        for (int r = 0; r < 8; ++r) gs[j * 9 + r] = acc[r];
    }
    __syncthreads();

    // phase 3: GRU nonlinearity + LN(hnew)
    {
        int r = t >> 5, l = t & 31;
        float hnew[4];
        #pragma unroll
        for (int e = 0; e < 4; ++e) {
            int i = l * 4 + e;
            float ir = gs[i * 9 + r]         + bih[i];
            float hr = gs[(384 + i) * 9 + r] + bhh[i];
            float iz = gs[(128 + i) * 9 + r] + bih[128 + i];
            float hz = gs[(512 + i) * 9 + r] + bhh[128 + i];
            float in_= gs[(256 + i) * 9 + r] + bih[256 + i];
            float hn = gs[(640 + i) * 9 + r] + bhh[256 + i];
            float rr = 1.0f / (1.0f + __expf(-(ir + hr)));
            float zz = 1.0f / (1.0f + __expf(-(iz + hz)));
            float nn = tanhf(in_ + rr * hn);
            hnew[e] = (1.0f - zz) * nn + zz * hs[r][i];
        }
        float s  = hnew[0] + hnew[1] + hnew[2] + hnew[3];
        float sq = hnew[0]*hnew[0] + hnew[1]*hnew[1] + hnew[2]*hnew[2] + hnew[3]*hnew[3];
        #pragma unroll
        for (int m = 1; m <= 16; m <<= 1) { s += __shfl_xor(s, m); sq += __shfl_xor(sq, m); }
        float mu = s * (1.0f / 128.0f);
        float rs = rsqrtf(sq * (1.0f / 128.0f) - mu * mu + LN_EPS);
        #pragma unroll
        for (int e = 0; e < 4; ++e) {
            int i = l * 4 + e;
            us[r][i]  = hnew[e];
            lns[r][i] = (hnew[e] - mu) * rs * mlg[i] + mlb[i];
        }
    }
    __syncthreads();

    // phase 4: fc1 (128->256) + exact gelu; thread t = w1 row t
    {
        const float* W = w1 + (size_t)t * Dn;
        float acc[8] = {0.f,0.f,0.f,0.f,0.f,0.f,0.f,0.f};
        for (int d = 0; d < 128; d += 4) {
            float4 w4 = *(const float4*)(W + d);
            #pragma unroll
            for (int r = 0; r < 8; ++r) acc[r] += dot4(w4, *(const float4*)&lns[r][d]);
        }
        float bb = b1[t];
        #pragma unroll
        for (int r = 0; r < 8; ++r) {
            float x = acc[r] + bb;
            h1s[r * 260 + t] = 0.5f * x * (1.0f + erff(x * 0.70710678118654752f));
        }
    }
    __syncthreads();

    // phase 5: fc2 (256->128) + residual + store
    {
        int c = t & 127, rb = (t >> 7) * 4;
        const float* W = w2 + (size_t)c * Hn;
        float acc[4] = {0.f, 0.f, 0.f, 0.f};
        for (int d = 0; d < 256; d += 4) {
            float4 w4 = *(const float4*)(W + d);
            #pragma unroll
            for (int rr = 0; rr < 4; ++rr)
                acc[rr] += dot4(w4, *(const float4*)&h1s[(rb + rr) * 260 + d]);
        }
        float bb = b2[c];
        #pragma unroll
        for (int rr = 0; rr < 4; ++rr) {
            int r = rb + rr;
            float o = us[r][c] + acc[rr] + bb;
            outp[(size_t)(bs0 + r) * Dn + c] = o;
            if (do_q) sn[r * 132 + c] = o;
        }
    }

    if (do_q) {
        __syncthreads();
        // phase 6: LN(snew) -> lns (reused)
        {
            int r = t >> 5, c = (t & 31) * 4;
            float4 x4 = *(const float4*)&sn[r * 132 + c];
            float s  = x4.x + x4.y + x4.z + x4.w;
            float sq = x4.x*x4.x + x4.y*x4.y + x4.z*x4.z + x4.w*x4.w;
            #pragma unroll
            for (int m = 1; m <= 16; m <<= 1) { s += __shfl_xor(s, m); sq += __shfl_xor(sq, m); }
            float mu = s * (1.0f / 128.0f);
            float rs = rsqrtf(sq * (1.0f / 128.0f) - mu * mu + LN_EPS);
            lns[r][c+0] = (x4.x - mu) * rs * ns_g[c+0] + ns_b[c+0];
            lns[r][c+1] = (x4.y - mu) * rs * ns_g[c+1] + ns_b[c+1];
            lns[r][c+2] = (x4.z - mu) * rs * ns_g[c+2] + ns_b[c+2];
            lns[r][c+3] = (x4.w - mu) * rs * ns_g[c+3] + ns_b[c+3];
        }
        __syncthreads();
        // phase 7: q = lns @ wq.T + bq
        {
            int c = t & 127, rb = (t >> 7) * 4;
            const float* W = wq + (size_t)c * Dn;
            float acc[4] = {0.f, 0.f, 0.f, 0.f};
            for (int d = 0; d < 128; d += 4) {
                float4 w4 = *(const float4*)(W + d);
                #pragma unroll
                for (int rr = 0; rr < 4; ++rr) acc[rr] += dot4(w4, *(const float4*)&lns[rb + rr][d]);
            }
            float bb = bq[c];
            #pragma unroll
            for (int rr = 0; rr < 4; ++rr)
                qbuf[(size_t)(bs0 + rb + rr) * Dn + c] = acc[rr] + bb;
        }
        // phase 8: zero accumulators for next iteration
        float4 z = {0.f, 0.f, 0.f, 0.f};
        *(float4*)&upd_zero[(size_t)bs0 * Dn + t * 4] = z;
        if (t < 8) norm_zero[bs0 + t] = 0.f;
    }
}

// ---------------------------------------------------------------------------
extern "C" void kernel_launch(void* const* d_in, const int* in_sizes, int n_in,
                              void* d_out, int out_size, void* d_ws, size_t ws_size,
                              hipStream_t stream) {
    (void)in_sizes; (void)n_in; (void)out_size; (void)ws_size;
    const float* inputs   = (const float*)d_in[0];
    const float* noise    = (const float*)d_in[1];
    const float* slots_mu = (const float*)d_in[2];
    const float* slots_ls = (const float*)d_in[3];
    const float* wq  = (const float*)d_in[4];
    const float* bq  = (const float*)d_in[5];
    const float* wk  = (const float*)d_in[6];
    const float* bk  = (const float*)d_in[7];
    const float* wv  = (const float*)d_in[8];
    const float* bv  = (const float*)d_in[9];
    const float* gwih = (const float*)d_in[10];
    const float* gwhh = (const float*)d_in[11];
    const float* gbih = (const float*)d_in[12];
    const float* gbhh = (const float*)d_in[13];
    const float* ns_g = (const float*)d_in[14];
    const float* ns_b = (const float*)d_in[15];
    const float* ni_g = (const float*)d_in[16];
    const float* ni_b = (const float*)d_in[17];
    const float* mlg  = (const float*)d_in[18];
    const float* mlb  = (const float*)d_in[19];
    const float* mw1  = (const float*)d_in[20];
    const float* mb1  = (const float*)d_in[21];
    const float* mw2  = (const float*)d_in[22];
    const float* mb2  = (const float*)d_in[23];

    float* ws      = (float*)d_ws;
    float* slots   = ws;                        // 65536 f
    float* qbuf    = ws + 65536;                // 65536 f
    float* updates = ws + 131072;               // 65536 f
    float* norm    = ws + 196608;               // 512 f
    ushort_t* wallT = (ushort_t*)(ws + 197120); // 32768 bf16
    ushort_t* kbuf = (ushort_t*)(ws + 262144);  // 33554432 bf16
    ushort_t* vbuf = (ushort_t*)(ws + 262144 + 16777216);

    k_slots_init<<<4, 256, 0, stream>>>(slots_mu, slots_ls, noise, slots);
    k_wprep<<<128, 256, 0, stream>>>(wk, wv, wallT);
    k_lnkv_mfma<<<4096, 256, 0, stream>>>(inputs, ni_g, ni_b, wallT, bk, bv, kbuf, vbuf);
    k_qproj2<<<64, 256, 0, stream>>>(slots, ns_g, ns_b, wq, bq, qbuf, updates, norm);
    for (int iter = 0; iter < 3; ++iter) {
        k_attn<<<dim3(32, 64), 256, 0, stream>>>(kbuf, vbuf, qbuf, updates, norm);
        float* outp = (iter == 2) ? (float*)d_out : slots;
        k_update2<<<64, 256, 0, stream>>>(slots, updates, norm, gwih, gwhh, gbih, gbhh,
                                          mlg, mlb, mw1, mb1, mw2, mb2, ns_g, ns_b, wq, bq,
                                          outp, qbuf, updates, norm, (iter == 2) ? 0 : 1);
    }
}

// Round 4
// 603.818 us; speedup vs baseline: 1.6579x; 1.0159x over previous
//
#include <hip/hip_runtime.h>
#include <hip/hip_bf16.h>
#include <math.h>

#define Bn 64
#define Nn 4096
#define Dn 128
#define Sn 8
#define Hn 256
#define LN_EPS 1e-5f
#define KS_S 136     // LDS row stride (bf16 elems) for x tiles
#define QSCALE 0.08838834764831845f  // 1/sqrt(128), pre-applied to q

typedef __bf16 bf16x8 __attribute__((ext_vector_type(8)));
typedef float f32x4 __attribute__((ext_vector_type(4)));
typedef unsigned short ushort_t;

__device__ __forceinline__ float dot4(float4 a, float4 b) {
    return a.x*b.x + a.y*b.y + a.z*b.z + a.w*b.w;
}
__device__ __forceinline__ ushort_t f2bf(float f) {
    __bf16 b = (__bf16)f;
    ushort_t u; __builtin_memcpy(&u, &b, 2); return u;
}
__device__ __forceinline__ float bf2f(ushort_t u) {
    unsigned int x = ((unsigned int)u) << 16; float f; __builtin_memcpy(&f, &x, 4); return f;
}
__device__ __forceinline__ bf16x8 zero8() {
    bf16x8 z;
    #pragma unroll
    for (int i = 0; i < 8; ++i) z[i] = (__bf16)0.0f;
    return z;
}

// ---------------------------------------------------------------------------
// K0: slots = mu + exp(log_sigma) * noise, broadcast over batch
__global__ void k_slots_init(const float* __restrict__ mu, const float* __restrict__ ls,
                             const float* __restrict__ noise, float* __restrict__ slots) {
    int i = blockIdx.x * blockDim.x + threadIdx.x;
    if (i < Sn * Dn) {
        float v = mu[i] + __expf(ls[i]) * noise[i];
        #pragma unroll 4
        for (int b = 0; b < Bn; ++b) slots[b * Sn * Dn + i] = v;
    }
}

// ---------------------------------------------------------------------------
// Kw: pack [wk; wv] -> bf16 in MFMA A-fragment order (coalesced frag loads)
__global__ void k_wprep(const float* __restrict__ wk, const float* __restrict__ wv,
                        ushort_t* __restrict__ wallT) {
    int o = blockIdx.x * blockDim.x + threadIdx.x;  // 32768
    if (o < 32768) {
        int e = o & 7;
        int l = (o >> 3) & 15;
        int q = (o >> 7) & 3;
        int k = (o >> 9) & 3;
        int G = o >> 11;
        int row = G * 16 + l;
        int col = k * 32 + q * 8 + e;
        float f = (row < 128) ? wk[row * 128 + col] : wv[(row - 128) * 128 + col];
        wallT[o] = f2bf(f);
    }
}

// ---------------------------------------------------------------------------
// K1: LN + K/V projection. k stored row-major [b*N+n][d] bf16;
// v stored TRANSPOSED [b][d][n] bf16 (operand-swapped MFMA gives D[n][d]->
// lane holds 4 consecutive n at fixed d = packed 8B store).
__global__ __launch_bounds__(256) void k_lnkv_mfma(
    const float* __restrict__ inp, const float* __restrict__ ni_g, const float* __restrict__ ni_b,
    const ushort_t* __restrict__ wallT, const float* __restrict__ bk, const float* __restrict__ bv,
    ushort_t* __restrict__ kout, ushort_t* __restrict__ vtout)
{
    __shared__ ushort_t xs[64 * KS_S];
    __shared__ float stats[128];
    __shared__ float gb[256];
    const int t = threadIdx.x;
    const int rowbase = blockIdx.x * 64;  // 4096 blocks, 64 blocks per batch

    gb[t] = (t < 128) ? ni_g[t] : ni_b[t - 128];

    const float* src = inp + (size_t)rowbase * Dn;
    float4 xv[8];
    #pragma unroll
    for (int it = 0; it < 8; ++it) {
        int f = it * 256 + t;
        float4 x4 = ((const float4*)src)[f];
        xv[it] = x4;
        float s  = x4.x + x4.y + x4.z + x4.w;
        float sq = x4.x*x4.x + x4.y*x4.y + x4.z*x4.z + x4.w*x4.w;
        #pragma unroll
        for (int m = 1; m <= 16; m <<= 1) { s += __shfl_xor(s, m); sq += __shfl_xor(sq, m); }
        if ((t & 31) == 0) {
            int r = it * 8 + (t >> 5);
            float mu  = s * (1.0f / 128.0f);
            float var = sq * (1.0f / 128.0f) - mu * mu;
            stats[2 * r]     = mu;
            stats[2 * r + 1] = rsqrtf(var + LN_EPS);
        }
    }
    __syncthreads();
    #pragma unroll
    for (int it = 0; it < 8; ++it) {
        int f = it * 256 + t;
        int r = f >> 5;
        int c = (f & 31) * 4;
        float mu = stats[2 * r], rs = stats[2 * r + 1];
        float4 x4 = xv[it];
        ushort4 o = { f2bf((x4.x - mu) * rs * gb[c + 0] + gb[128 + c + 0]),
                      f2bf((x4.y - mu) * rs * gb[c + 1] + gb[128 + c + 1]),
                      f2bf((x4.z - mu) * rs * gb[c + 2] + gb[128 + c + 2]),
                      f2bf((x4.w - mu) * rs * gb[c + 3] + gb[128 + c + 3]) };
        *(ushort4*)&xs[r * KS_S + c] = o;
    }
    __syncthreads();

    const int lane = t & 63;
    const int w = t >> 6;
    const int colw = w * 64;             // waves 0,1 -> k cols; 2,3 -> v cols
    const int l15 = lane & 15, q = lane >> 4;
    const bool is_k = (colw < 128);
    const int b_idx = rowbase >> 12;
    const int nloc0 = rowbase & 4095;

    bf16x8 afr[4][4];
    #pragma unroll
    for (int ct = 0; ct < 4; ++ct) {
        int G = w * 4 + ct;
        #pragma unroll
        for (int k = 0; k < 4; ++k)
            afr[ct][k] = *(const bf16x8*)&wallT[(size_t)((G * 4 + k) * 64 + lane) * 8];
    }
    float4 biask[4];
    float biasv[4];
    #pragma unroll
    for (int ct = 0; ct < 4; ++ct) {
        if (is_k) biask[ct] = *(const float4*)&bk[colw + ct * 16 + q * 4];
        else      biasv[ct] = bv[colw - 128 + ct * 16 + l15];
    }

    #pragma unroll
    for (int rt = 0; rt < 4; ++rt) {
        bf16x8 bfr[4];
        #pragma unroll
        for (int k = 0; k < 4; ++k)
            bfr[k] = *(const bf16x8*)&xs[(rt * 16 + l15) * KS_S + k * 32 + q * 8];
        #pragma unroll
        for (int ct = 0; ct < 4; ++ct) {
            f32x4 acc = {0.f, 0.f, 0.f, 0.f};
            if (is_k) {
                #pragma unroll
                for (int k = 0; k < 4; ++k)
                    acc = __builtin_amdgcn_mfma_f32_16x16x32_bf16(afr[ct][k], bfr[k], acc, 0, 0, 0);
                // D[w-col][x-row]: lane = row rowbase+rt*16+l15, cols colw+ct*16+q*4..+3
                size_t grow = (size_t)rowbase + rt * 16 + l15;
                int c0 = colw + ct * 16 + q * 4;
                ushort4 o = { f2bf(acc[0] + biask[ct].x), f2bf(acc[1] + biask[ct].y),
                              f2bf(acc[2] + biask[ct].z), f2bf(acc[3] + biask[ct].w) };
                *(ushort4*)&kout[grow * Dn + c0] = o;
            } else {
                #pragma unroll
                for (int k = 0; k < 4; ++k)
                    acc = __builtin_amdgcn_mfma_f32_16x16x32_bf16(bfr[k], afr[ct][k], acc, 0, 0, 0);
                // D[x-row][w-col]: lane = d (colw-128+ct*16+l15), rows n = rt*16+q*4..+3
                int d = colw - 128 + ct * 16 + l15;
                int n4 = nloc0 + rt * 16 + q * 4;
                float bb = biasv[ct];
                ushort4 o = { f2bf(acc[0] + bb), f2bf(acc[1] + bb),
                              f2bf(acc[2] + bb), f2bf(acc[3] + bb) };
                *(ushort4*)&vtout[((size_t)b_idx * Dn + d) * Nn + n4] = o;
            }
        }
    }
}

// ---------------------------------------------------------------------------
// K2: q = LN(slots)@wq.T + bq, stored bf16 pre-scaled by 1/sqrt(D).
// 8 rows/block (64 blocks x 256 thr); zeroes updates/norm accumulators.
__global__ __launch_bounds__(256) void k_qproj2(
    const float* __restrict__ slots, const float* __restrict__ ns_g, const float* __restrict__ ns_b,
    const float* __restrict__ wq, const float* __restrict__ bq,
    ushort_t* __restrict__ qb, float* __restrict__ updates, float* __restrict__ norm)
{
    __shared__ float lnq[8][128];
    const int t = threadIdx.x;
    const int bs0 = blockIdx.x * 8;
    {
        int r = t >> 5, c = (t & 31) * 4;
        float4 x4 = *(const float4*)&slots[(size_t)(bs0 + r) * Dn + c];
        float s  = x4.x + x4.y + x4.z + x4.w;
        float sq = x4.x*x4.x + x4.y*x4.y + x4.z*x4.z + x4.w*x4.w;
        #pragma unroll
        for (int m = 1; m <= 16; m <<= 1) { s += __shfl_xor(s, m); sq += __shfl_xor(sq, m); }
        float mu = s * (1.0f / 128.0f);
        float rs = rsqrtf(sq * (1.0f / 128.0f) - mu * mu + LN_EPS);
        lnq[r][c+0] = (x4.x - mu) * rs * ns_g[c+0] + ns_b[c+0];
        lnq[r][c+1] = (x4.y - mu) * rs * ns_g[c+1] + ns_b[c+1];
        lnq[r][c+2] = (x4.z - mu) * rs * ns_g[c+2] + ns_b[c+2];
        lnq[r][c+3] = (x4.w - mu) * rs * ns_g[c+3] + ns_b[c+3];
    }
    __syncthreads();
    {
        int c = t & 127, rb = (t >> 7) * 4;
        const float* W = wq + (size_t)c * Dn;
        float acc[4] = {0.f, 0.f, 0.f, 0.f};
        for (int d = 0; d < 128; d += 4) {
            float4 w4 = *(const float4*)(W + d);
            #pragma unroll
            for (int rr = 0; rr < 4; ++rr) acc[rr] += dot4(w4, *(const float4*)&lnq[rb + rr][d]);
        }
        float bb = bq[c];
        #pragma unroll
        for (int rr = 0; rr < 4; ++rr)
            qb[(size_t)(bs0 + rb + rr) * Dn + c] = f2bf((acc[rr] + bb) * QSCALE);
    }
    float4 z = {0.f, 0.f, 0.f, 0.f};
    *(float4*)&updates[(size_t)bs0 * Dn + t * 4] = z;
    if (t < 8) norm[bs0 + t] = 0.f;
}

// ---------------------------------------------------------------------------
// K3: MFMA attention. grid (32 chunks, 64 batches), 256 thr (4 waves),
// 128 n-rows/block (32 per wave). No k/v LDS staging: B-frags direct from
// global (quads complete 64B segments). p round-trips a 4KB LDS tile.
__global__ __launch_bounds__(256) void k_attn_mfma(
    const ushort_t* __restrict__ kbuf,   // [b][n][128] bf16
    const ushort_t* __restrict__ vtbuf,  // [b][d][4096] bf16
    const ushort_t* __restrict__ qb,     // [b][8][128] bf16, pre-scaled
    float* __restrict__ updates, float* __restrict__ norm)
{
    __shared__ ushort_t ps[16 * KS_S];   // p: [s][n] (rows 8..15 zeroed pad)
    const int t = threadIdx.x;
    const int b = blockIdx.y;
    const int chunk = blockIdx.x;
    const int lane = t & 63;
    const int w = t >> 6;
    const int l15 = lane & 15;
    const int q = lane >> 4;
    const int nblock = chunk * 128;

    // zero padding rows 8..15 of ps (A-frag reads touch them)
    for (int i = t; i < 8 * KS_S; i += 256) ps[8 * KS_S + i] = 0;

    // A operand: q fragments (slot entities; 8..15 -> zero)
    bf16x8 aq[4];
    #pragma unroll
    for (int c = 0; c < 4; ++c) {
        bf16x8 z = zero8();
        if (l15 < 8)
            z = *(const bf16x8*)&qb[((size_t)b * Sn + l15) * Dn + c * 32 + q * 8];
        aq[c] = z;
    }

    const size_t kbase = ((size_t)b * Nn + nblock) * Dn;
    float nacc[4] = {0.f, 0.f, 0.f, 0.f};

    #pragma unroll
    for (int g = 0; g < 2; ++g) {
        int nloc = w * 32 + g * 16 + l15;     // row within 128-tile
        f32x4 lg = {0.f, 0.f, 0.f, 0.f};
        #pragma unroll
        for (int c = 0; c < 4; ++c) {
            bf16x8 bk = *(const bf16x8*)&kbuf[kbase + (size_t)nloc * Dn + c * 32 + q * 8];
            lg = __builtin_amdgcn_mfma_f32_16x16x32_bf16(aq[c], bk, lg, 0, 0, 0);
        }
        // lane holds logits for slots q*4..q*4+3 at row nloc (quads 0,1 real)
        float mown = fmaxf(fmaxf(lg[0], lg[1]), fmaxf(lg[2], lg[3]));
        float m8 = fmaxf(mown, __shfl_xor(mown, 16));
        float p0 = __expf(lg[0] - m8), p1 = __expf(lg[1] - m8);
        float p2 = __expf(lg[2] - m8), p3 = __expf(lg[3] - m8);
        float sown = p0 + p1 + p2 + p3;
        float inv = 1.0f / (sown + __shfl_xor(sown, 16));
        if (q < 2) {
            ushort_t u0 = f2bf(p0 * inv), u1 = f2bf(p1 * inv);
            ushort_t u2 = f2bf(p2 * inv), u3 = f2bf(p3 * inv);
            int s0 = q * 4;
            ps[(s0 + 0) * KS_S + nloc] = u0;
            ps[(s0 + 1) * KS_S + nloc] = u1;
            ps[(s0 + 2) * KS_S + nloc] = u2;
            ps[(s0 + 3) * KS_S + nloc] = u3;
            nacc[0] += bf2f(u0); nacc[1] += bf2f(u1);
            nacc[2] += bf2f(u2); nacc[3] += bf2f(u3);
        }
    }

    // per-slot norm partial sums (use bf16-rounded p for consistency)
    if (q < 2) {
        #pragma unroll
        for (int r = 0; r < 4; ++r) {
            float v = nacc[r];
            v += __shfl_xor(v, 1); v += __shfl_xor(v, 2);
            v += __shfl_xor(v, 4); v += __shfl_xor(v, 8);
            nacc[r] = v;
        }
        if (l15 == 0) {
            #pragma unroll
            for (int r = 0; r < 4; ++r)
                atomicAdd(norm + b * Sn + q * 4 + r, nacc[r]);
        }
    }
    __syncthreads();

    // PV: A = p (slot entities), B = v^T (d entities), K = 128 n
    bf16x8 pa[4];
    #pragma unroll
    for (int c = 0; c < 4; ++c)
        pa[c] = *(const bf16x8*)&ps[l15 * KS_S + c * 32 + q * 8];

    const size_t vtb = (size_t)b * Dn * Nn + nblock;
    #pragma unroll
    for (int g2 = 0; g2 < 2; ++g2) {
        int d = w * 32 + g2 * 16 + l15;
        f32x4 uacc = {0.f, 0.f, 0.f, 0.f};
        #pragma unroll
        for (int c = 0; c < 4; ++c) {
            bf16x8 bvv = *(const bf16x8*)&vtbuf[vtb + (size_t)d * Nn + c * 32 + q * 8];
            uacc = __builtin_amdgcn_mfma_f32_16x16x32_bf16(pa[c], bvv, uacc, 0, 0, 0);
        }
        if (q < 2) {
            float* up = updates + ((size_t)b * Sn + q * 4) * Dn + d;
            atomicAdd(up + 0 * Dn, uacc[0]);
            atomicAdd(up + 1 * Dn, uacc[1]);
            atomicAdd(up + 2 * Dn, uacc[2]);
            atomicAdd(up + 3 * Dn, uacc[3]);
        }
    }
}

// ---------------------------------------------------------------------------
// K4: GRU + LN + MLP + residual, 8 rows/block. If do_q: fused next-iter q
// (bf16, pre-scaled) + accumulator zeroing.
__global__ __launch_bounds__(256) void k_update2(
    const float* __restrict__ slots, const float* __restrict__ updates_in,
    const float* __restrict__ norm,
    const float* __restrict__ wih, const float* __restrict__ whh,
    const float* __restrict__ bih, const float* __restrict__ bhh,
    const float* __restrict__ mlg, const float* __restrict__ mlb,
    const float* __restrict__ w1, const float* __restrict__ b1,
    const float* __restrict__ w2, const float* __restrict__ b2,
    const float* __restrict__ ns_g, const float* __restrict__ ns_b,
    const float* __restrict__ wq, const float* __restrict__ bq,
    float* __restrict__ outp, ushort_t* __restrict__ qb,
    float* __restrict__ upd_zero, float* __restrict__ norm_zero, int do_q)
{
    __shared__ float us[8][128];
    __shared__ float hs[8][128];
    __shared__ float gs[768 * 9];
    __shared__ float lns[8][128];
    __shared__ float h1s[8 * 260];
    __shared__ float sn[8 * 132];
    const int t = threadIdx.x;
    const int bs0 = blockIdx.x * 8;

    {
        int r = t >> 5, c = (t & 31) * 4;
        float inv = 1.0f / fmaxf(norm[bs0 + r], 1e-8f);
        float4 u4 = *(const float4*)&updates_in[(size_t)(bs0 + r) * Dn + c];
        float4 h4 = *(const float4*)&slots[(size_t)(bs0 + r) * Dn + c];
        u4.x *= inv; u4.y *= inv; u4.z *= inv; u4.w *= inv;
        *(float4*)&us[r][c] = u4;
        *(float4*)&hs[r][c] = h4;
    }
    __syncthreads();

    #pragma unroll
    for (int jj = 0; jj < 3; ++jj) {
        int j = t + jj * 256;
        const float* W = (j < 384) ? (wih + (size_t)j * Dn) : (whh + (size_t)(j - 384) * Dn);
        const float* X = (j < 384) ? &us[0][0] : &hs[0][0];
        float acc[8] = {0.f,0.f,0.f,0.f,0.f,0.f,0.f,0.f};
        for (int d = 0; d < 128; d += 4) {
            float4 w4 = *(const float4*)(W + d);
            #pragma unroll
            for (int r = 0; r < 8; ++r)
                acc[r] += dot4(w4, *(const float4*)(X + r * 128 + d));
        }
        #pragma unroll
        for (int r = 0; r < 8; ++r) gs[j * 9 + r] = acc[r];
    }
    __syncthreads();

    {
        int r = t >> 5, l = t & 31;
        float hnew[4];
        #pragma unroll
        for (int e = 0; e < 4; ++e) {
            int i = l * 4 + e;
            float ir = gs[i * 9 + r]         + bih[i];
            float hr = gs[(384 + i) * 9 + r] + bhh[i];
            float iz = gs[(128 + i) * 9 + r] + bih[128 + i];
            float hz = gs[(512 + i) * 9 + r] + bhh[128 + i];
            float in_= gs[(256 + i) * 9 + r] + bih[256 + i];
            float hn = gs[(640 + i) * 9 + r] + bhh[256 + i];
            float rr = 1.0f / (1.0f + __expf(-(ir + hr)));
            float zz = 1.0f / (1.0f + __expf(-(iz + hz)));
            float nn = tanhf(in_ + rr * hn);
            hnew[e] = (1.0f - zz) * nn + zz * hs[r][i];
        }
        float s  = hnew[0] + hnew[1] + hnew[2] + hnew[3];
        float sq = hnew[0]*hnew[0] + hnew[1]*hnew[1] + hnew[2]*hnew[2] + hnew[3]*hnew[3];
        #pragma unroll
        for (int m = 1; m <= 16; m <<= 1) { s += __shfl_xor(s, m); sq += __shfl_xor(sq, m); }
        float mu = s * (1.0f / 128.0f);
        float rs = rsqrtf(sq * (1.0f / 128.0f) - mu * mu + LN_EPS);
        #pragma unroll
        for (int e = 0; e < 4; ++e) {
            int i = l * 4 + e;
            us[r][i]  = hnew[e];
            lns[r][i] = (hnew[e] - mu) * rs * mlg[i] + mlb[i];
        }
    }
    __syncthreads();

    {
        const float* W = w1 + (size_t)t * Dn;
        float acc[8] = {0.f,0.f,0.f,0.f,0.f,0.f,0.f,0.f};
        for (int d = 0; d < 128; d += 4) {
            float4 w4 = *(const float4*)(W + d);
            #pragma unroll
            for (int r = 0; r < 8; ++r) acc[r] += dot4(w4, *(const float4*)&lns[r][d]);
        }
        float bb = b1[t];
        #pragma unroll
        for (int r = 0; r < 8; ++r) {
            float x = acc[r] + bb;
            h1s[r * 260 + t] = 0.5f * x * (1.0f + erff(x * 0.70710678118654752f));
        }
    }
    __syncthreads();

    {
        int c = t & 127, rb = (t >> 7) * 4;
        const float* W = w2 + (size_t)c * Hn;
        float acc[4] = {0.f, 0.f, 0.f, 0.f};
        for (int d = 0; d < 256; d += 4) {
            float4 w4 = *(const float4*)(W + d);
            #pragma unroll
            for (int rr = 0; rr < 4; ++rr)
                acc[rr] += dot4(w4, *(const float4*)&h1s[(rb + rr) * 260 + d]);
        }
        float bb = b2[c];
        #pragma unroll
        for (int rr = 0; rr < 4; ++rr) {
            int r = rb + rr;
            float o = us[r][c] + acc[rr] + bb;
            outp[(size_t)(bs0 + r) * Dn + c] = o;
            if (do_q) sn[r * 132 + c] = o;
        }
    }

    if (do_q) {
        __syncthreads();
        {
            int r = t >> 5, c = (t & 31) * 4;
            float4 x4 = *(const float4*)&sn[r * 132 + c];
            float s  = x4.x + x4.y + x4.z + x4.w;
            float sq = x4.x*x4.x + x4.y*x4.y + x4.z*x4.z + x4.w*x4.w;
            #pragma unroll
            for (int m = 1; m <= 16; m <<= 1) { s += __shfl_xor(s, m); sq += __shfl_xor(sq, m); }
            float mu = s * (1.0f / 128.0f);
            float rs = rsqrtf(sq * (1.0f / 128.0f) - mu * mu + LN_EPS);
            lns[r][c+0] = (x4.x - mu) * rs * ns_g[c+0] + ns_b[c+0];
            lns[r][c+1] = (x4.y - mu) * rs * ns_g[c+1] + ns_b[c+1];
            lns[r][c+2] = (x4.z - mu) * rs * ns_g[c+2] + ns_b[c+2];
            lns[r][c+3] = (x4.w - mu) * rs * ns_g[c+3] + ns_b[c+3];
        }
        __syncthreads();
        {
            int c = t & 127, rb = (t >> 7) * 4;
            const float* W = wq + (size_t)c * Dn;
            float acc[4] = {0.f, 0.f, 0.f, 0.f};
            for (int d = 0; d < 128; d += 4) {
                float4 w4 = *(const float4*)(W + d);
                #pragma unroll
                for (int rr = 0; rr < 4; ++rr) acc[rr] += dot4(w4, *(const float4*)&lns[rb + rr][d]);
            }
            float bb = bq[c];
            #pragma unroll
            for (int rr = 0; rr < 4; ++rr)
                qb[(size_t)(bs0 + rb + rr) * Dn + c] = f2bf((acc[rr] + bb) * QSCALE);
        }
        float4 z = {0.f, 0.f, 0.f, 0.f};
        *(float4*)&upd_zero[(size_t)bs0 * Dn + t * 4] = z;
        if (t < 8) norm_zero[bs0 + t] = 0.f;
    }
}

// ---------------------------------------------------------------------------
extern "C" void kernel_launch(void* const* d_in, const int* in_sizes, int n_in,
                              void* d_out, int out_size, void* d_ws, size_t ws_size,
                              hipStream_t stream) {
    (void)in_sizes; (void)n_in; (void)out_size; (void)ws_size;
    const float* inputs   = (const float*)d_in[0];
    const float* noise    = (const float*)d_in[1];
    const float* slots_mu = (const float*)d_in[2];
    const float* slots_ls = (const float*)d_in[3];
    const float* wq  = (const float*)d_in[4];
    const float* bq  = (const float*)d_in[5];
    const float* wk  = (const float*)d_in[6];
    const float* bk  = (const float*)d_in[7];
    const float* wv  = (const float*)d_in[8];
    const float* bv  = (const float*)d_in[9];
    const float* gwih = (const float*)d_in[10];
    const float* gwhh = (const float*)d_in[11];
    const float* gbih = (const float*)d_in[12];
    const float* gbhh = (const float*)d_in[13];
    const float* ns_g = (const float*)d_in[14];
    const float* ns_b = (const float*)d_in[15];
    const float* ni_g = (const float*)d_in[16];
    const float* ni_b = (const float*)d_in[17];
    const float* mlg  = (const float*)d_in[18];
    const float* mlb  = (const float*)d_in[19];
    const float* mw1  = (const float*)d_in[20];
    const float* mb1  = (const float*)d_in[21];
    const float* mw2  = (const float*)d_in[22];
    const float* mb2  = (const float*)d_in[23];

    float* ws      = (float*)d_ws;
    float* slots   = ws;                          // 65536 f
    float* updates = ws + 65536;                  // 65536 f
    float* norm    = ws + 131072;                 // 512 f
    ushort_t* qb   = (ushort_t*)(ws + 131584);    // 65536 bf16
    ushort_t* wallT = (ushort_t*)(ws + 164352);   // 32768 bf16
    ushort_t* kbuf  = (ushort_t*)(ws + 262144);   // [b][n][d] bf16
    ushort_t* vtbuf = (ushort_t*)(ws + 262144 + 16777216);  // [b][d][n] bf16

    k_slots_init<<<4, 256, 0, stream>>>(slots_mu, slots_ls, noise, slots);
    k_wprep<<<128, 256, 0, stream>>>(wk, wv, wallT);
    k_lnkv_mfma<<<4096, 256, 0, stream>>>(inputs, ni_g, ni_b, wallT, bk, bv, kbuf, vtbuf);
    k_qproj2<<<64, 256, 0, stream>>>(slots, ns_g, ns_b, wq, bq, qb, updates, norm);
    for (int iter = 0; iter < 3; ++iter) {
        k_attn_mfma<<<dim3(32, 64), 256, 0, stream>>>(kbuf, vtbuf, qb, updates, norm);
        float* outp = (iter == 2) ? (float*)d_out : slots;
        k_update2<<<64, 256, 0, stream>>>(slots, updates, norm, gwih, gwhh, gbih, gbhh,
                                          mlg, mlb, mw1, mb1, mw2, mb2, ns_g, ns_b, wq, bq,
                                          outp, qb, updates, norm, (iter == 2) ? 0 : 1);
    }
}

// Round 5
// 481.347 us; speedup vs baseline: 2.0797x; 1.2544x over previous
//
#include <hip/hip_runtime.h>
#include <hip/hip_bf16.h>
#include <math.h>

#define Bn 64
#define Nn 4096
#define Dn 128
#define Sn 8
#define Hn 256
#define LN_EPS 1e-5f
#define KS_S 136
#define QSCALE 0.08838834764831845f  // 1/sqrt(128), pre-applied to q

typedef __bf16 bf16x8 __attribute__((ext_vector_type(8)));
typedef float f32x4 __attribute__((ext_vector_type(4)));
typedef unsigned short ushort_t;

__device__ __forceinline__ float dot4(float4 a, float4 b) {
    return a.x*b.x + a.y*b.y + a.z*b.z + a.w*b.w;
}
__device__ __forceinline__ ushort_t f2bf(float f) {
    __bf16 b = (__bf16)f;
    ushort_t u; __builtin_memcpy(&u, &b, 2); return u;
}
__device__ __forceinline__ float bf2f(ushort_t u) {
    unsigned int x = ((unsigned int)u) << 16; float f; __builtin_memcpy(&f, &x, 4); return f;
}
__device__ __forceinline__ bf16x8 zero8() {
    bf16x8 z;
    #pragma unroll
    for (int i = 0; i < 8; ++i) z[i] = (__bf16)0.0f;
    return z;
}

// ---------------------------------------------------------------------------
// K0: slots = mu + exp(log_sigma) * noise, broadcast over batch
__global__ void k_slots_init(const float* __restrict__ mu, const float* __restrict__ ls,
                             const float* __restrict__ noise, float* __restrict__ slots) {
    int i = blockIdx.x * blockDim.x + threadIdx.x;
    if (i < Sn * Dn) {
        float v = mu[i] + __expf(ls[i]) * noise[i];
        #pragma unroll 4
        for (int b = 0; b < Bn; ++b) slots[b * Sn * Dn + i] = v;
    }
}

// ---------------------------------------------------------------------------
// Kw: pack [wk; wv] -> bf16 in MFMA A-fragment order
__global__ void k_wprep(const float* __restrict__ wk, const float* __restrict__ wv,
                        ushort_t* __restrict__ wallT) {
    int o = blockIdx.x * blockDim.x + threadIdx.x;  // 32768
    if (o < 32768) {
        int e = o & 7;
        int l = (o >> 3) & 15;
        int q = (o >> 7) & 3;
        int k = (o >> 9) & 3;
        int G = o >> 11;
        int row = G * 16 + l;
        int col = k * 32 + q * 8 + e;
        float f = (row < 128) ? wk[row * 128 + col] : wv[(row - 128) * 128 + col];
        wallT[o] = f2bf(f);
    }
}

// ---------------------------------------------------------------------------
// K1: LN + K/V projection. OUTPUTS IN MFMA B-FRAGMENT ORDER:
//  k: kfrag[(ngrp*4 + c)*512 + lane*8 + e]   ngrp = global_row>>4, c = d>>5,
//     lane = ((d>>3)&3)*16 + (n&15), e = d&7   -> attn QK loads are lane-contig.
//  v: vfrag[((b*8+dgrp)*128 + nc)*512 + lane*8 + e]  dgrp=d>>4, nc=n>>5 (local),
//     lane = ((n>>3)&3)*16 + (d&15), e = n&7   -> attn PV loads are lane-contig.
// All stores are 512B-contiguous per (rt,ct) quad-group.
__global__ __launch_bounds__(256) void k_lnkv_mfma(
    const float* __restrict__ inp, const float* __restrict__ ni_g, const float* __restrict__ ni_b,
    const ushort_t* __restrict__ wallT, const float* __restrict__ bk, const float* __restrict__ bv,
    ushort_t* __restrict__ kout, ushort_t* __restrict__ vout)
{
    __shared__ ushort_t xs[64 * KS_S];
    __shared__ float stats[128];
    __shared__ float gb[256];
    const int t = threadIdx.x;
    const int rowbase = blockIdx.x * 64;  // 4096 blocks

    gb[t] = (t < 128) ? ni_g[t] : ni_b[t - 128];

    const float* src = inp + (size_t)rowbase * Dn;
    float4 xv[8];
    #pragma unroll
    for (int it = 0; it < 8; ++it) {
        int f = it * 256 + t;
        float4 x4 = ((const float4*)src)[f];
        xv[it] = x4;
        float s  = x4.x + x4.y + x4.z + x4.w;
        float sq = x4.x*x4.x + x4.y*x4.y + x4.z*x4.z + x4.w*x4.w;
        #pragma unroll
        for (int m = 1; m <= 16; m <<= 1) { s += __shfl_xor(s, m); sq += __shfl_xor(sq, m); }
        if ((t & 31) == 0) {
            int r = it * 8 + (t >> 5);
            float mu  = s * (1.0f / 128.0f);
            float var = sq * (1.0f / 128.0f) - mu * mu;
            stats[2 * r]     = mu;
            stats[2 * r + 1] = rsqrtf(var + LN_EPS);
        }
    }
    __syncthreads();
    #pragma unroll
    for (int it = 0; it < 8; ++it) {
        int f = it * 256 + t;
        int r = f >> 5;
        int c = (f & 31) * 4;
        float mu = stats[2 * r], rs = stats[2 * r + 1];
        float4 x4 = xv[it];
        ushort4 o = { f2bf((x4.x - mu) * rs * gb[c + 0] + gb[128 + c + 0]),
                      f2bf((x4.y - mu) * rs * gb[c + 1] + gb[128 + c + 1]),
                      f2bf((x4.z - mu) * rs * gb[c + 2] + gb[128 + c + 2]),
                      f2bf((x4.w - mu) * rs * gb[c + 3] + gb[128 + c + 3]) };
        *(ushort4*)&xs[r * KS_S + c] = o;
    }
    __syncthreads();

    const int lane = t & 63;
    const int w = t >> 6;
    const int colw = w * 64;             // waves 0,1 -> k cols; 2,3 -> v cols
    const int l15 = lane & 15, q = lane >> 4;
    const bool is_k = (colw < 128);
    const int b_idx = rowbase >> 12;
    const int nloc0 = rowbase & 4095;

    bf16x8 afr[4][4];
    #pragma unroll
    for (int ct = 0; ct < 4; ++ct) {
        int G = w * 4 + ct;
        #pragma unroll
        for (int k = 0; k < 4; ++k)
            afr[ct][k] = *(const bf16x8*)&wallT[(size_t)((G * 4 + k) * 64 + lane) * 8];
    }
    float4 biask[4];
    float biasv[4];
    #pragma unroll
    for (int ct = 0; ct < 4; ++ct) {
        if (is_k) biask[ct] = *(const float4*)&bk[colw + ct * 16 + q * 4];
        else      biasv[ct] = bv[colw - 128 + ct * 16 + l15];
    }

    #pragma unroll
    for (int rt = 0; rt < 4; ++rt) {
        bf16x8 bfr[4];
        #pragma unroll
        for (int k = 0; k < 4; ++k)
            bfr[k] = *(const bf16x8*)&xs[(rt * 16 + l15) * KS_S + k * 32 + q * 8];
        #pragma unroll
        for (int ct = 0; ct < 4; ++ct) {
            f32x4 acc = {0.f, 0.f, 0.f, 0.f};
            if (is_k) {
                #pragma unroll
                for (int k = 0; k < 4; ++k)
                    acc = __builtin_amdgcn_mfma_f32_16x16x32_bf16(afr[ct][k], bfr[k], acc, 0, 0, 0);
                // element (n = rowbase+rt*16+l15, d = colw+ct*16+q*4+reg)
                int d0 = colw + ct * 16 + q * 4;
                int c  = d0 >> 5;
                int qd = (d0 >> 3) & 3;
                int e0 = d0 & 7;  // 0 or 4
                ushort4 o = { f2bf(acc[0] + biask[ct].x), f2bf(acc[1] + biask[ct].y),
                              f2bf(acc[2] + biask[ct].z), f2bf(acc[3] + biask[ct].w) };
                size_t off = ((size_t)(((rowbase >> 4) + rt) * 4 + c) * 64 + qd * 16 + l15) * 8 + e0;
                *(ushort4*)&kout[off] = o;
            } else {
                #pragma unroll
                for (int k = 0; k < 4; ++k)
                    acc = __builtin_amdgcn_mfma_f32_16x16x32_bf16(bfr[k], afr[ct][k], acc, 0, 0, 0);
                // element (d = (w-2)*64+ct*16+l15, n = nloc0+rt*16+q*4+reg)
                int dgrp = (w - 2) * 4 + ct;
                int n0 = nloc0 + rt * 16 + q * 4;
                int nc = n0 >> 5;
                int qn = (n0 >> 3) & 3;
                int e0 = n0 & 7;  // 0 or 4
                float bb = biasv[ct];
                ushort4 o = { f2bf(acc[0] + bb), f2bf(acc[1] + bb),
                              f2bf(acc[2] + bb), f2bf(acc[3] + bb) };
                size_t off = (((size_t)(b_idx * 8 + dgrp) * 128 + nc) * 64 + qn * 16 + l15) * 8 + e0;
                *(ushort4*)&vout[off] = o;
            }
        }
    }
}

// ---------------------------------------------------------------------------
// K2: initial q = LN(slots)@wq.T + bq, bf16 pre-scaled. 64 blocks x 256 thr.
__global__ __launch_bounds__(256) void k_qproj2(
    const float* __restrict__ slots, const float* __restrict__ ns_g, const float* __restrict__ ns_b,
    const float* __restrict__ wq, const float* __restrict__ bq,
    ushort_t* __restrict__ qb)
{
    __shared__ float lnq[8][128];
    const int t = threadIdx.x;
    const int bs0 = blockIdx.x * 8;
    {
        int r = t >> 5, c = (t & 31) * 4;
        float4 x4 = *(const float4*)&slots[(size_t)(bs0 + r) * Dn + c];
        float s  = x4.x + x4.y + x4.z + x4.w;
        float sq = x4.x*x4.x + x4.y*x4.y + x4.z*x4.z + x4.w*x4.w;
        #pragma unroll
        for (int m = 1; m <= 16; m <<= 1) { s += __shfl_xor(s, m); sq += __shfl_xor(sq, m); }
        float mu = s * (1.0f / 128.0f);
        float rs = rsqrtf(sq * (1.0f / 128.0f) - mu * mu + LN_EPS);
        lnq[r][c+0] = (x4.x - mu) * rs * ns_g[c+0] + ns_b[c+0];
        lnq[r][c+1] = (x4.y - mu) * rs * ns_g[c+1] + ns_b[c+1];
        lnq[r][c+2] = (x4.z - mu) * rs * ns_g[c+2] + ns_b[c+2];
        lnq[r][c+3] = (x4.w - mu) * rs * ns_g[c+3] + ns_b[c+3];
    }
    __syncthreads();
    {
        int c = t & 127, rb = (t >> 7) * 4;
        const float* W = wq + (size_t)c * Dn;
        float acc[4] = {0.f, 0.f, 0.f, 0.f};
        for (int d = 0; d < 128; d += 4) {
            float4 w4 = *(const float4*)(W + d);
            #pragma unroll
            for (int rr = 0; rr < 4; ++rr) acc[rr] += dot4(w4, *(const float4*)&lnq[rb + rr][d]);
        }
        float bb = bq[c];
        #pragma unroll
        for (int rr = 0; rr < 4; ++rr)
            qb[(size_t)(bs0 + rb + rr) * Dn + c] = f2bf((acc[rr] + bb) * QSCALE);
    }
}

// ---------------------------------------------------------------------------
// K3: MFMA attention, fragment-order k/v, atomic-free partial outputs.
// grid (8 chunks, 64 b), 256 thr. Each block: 512 n, 4 tiles of 128.
// PV accumulates across tiles in-register; writes upart[chunk][b][s][d].
__global__ __launch_bounds__(256) void k_attn_mfma(
    const ushort_t* __restrict__ kbuf, const ushort_t* __restrict__ vtbuf,
    const ushort_t* __restrict__ qb,
    float* __restrict__ upart, float* __restrict__ npart)
{
    __shared__ ushort_t ps[16 * KS_S];
    __shared__ float nsh[8];
    const int t = threadIdx.x;
    const int b = blockIdx.y;
    const int chunk = blockIdx.x;   // 0..7
    const int lane = t & 63;
    const int w = t >> 6;
    const int l15 = lane & 15;
    const int q = lane >> 4;

    for (int i = t; i < 8 * KS_S; i += 256) ps[8 * KS_S + i] = 0;
    if (t < 8) nsh[t] = 0.f;

    bf16x8 aq[4];
    #pragma unroll
    for (int c = 0; c < 4; ++c) {
        bf16x8 z = zero8();
        if (l15 < 8)
            z = *(const bf16x8*)&qb[((size_t)b * Sn + l15) * Dn + c * 32 + q * 8];
        aq[c] = z;
    }

    f32x4 acc[2];
    acc[0] = (f32x4){0.f, 0.f, 0.f, 0.f};
    acc[1] = (f32x4){0.f, 0.f, 0.f, 0.f};
    float nacc[4] = {0.f, 0.f, 0.f, 0.f};

    for (int nt = 0; nt < 4; ++nt) {
        __syncthreads();   // previous tile's pa reads done; ps safe to overwrite
        #pragma unroll
        for (int g = 0; g < 2; ++g) {
            int ng = chunk * 32 + nt * 8 + w * 2 + g;   // n>>4 within batch
            f32x4 lg = {0.f, 0.f, 0.f, 0.f};
            #pragma unroll
            for (int c = 0; c < 4; ++c) {
                bf16x8 bk = *(const bf16x8*)&kbuf[(((size_t)b * 256 + ng) * 4 + c) * 512 + lane * 8];
                lg = __builtin_amdgcn_mfma_f32_16x16x32_bf16(aq[c], bk, lg, 0, 0, 0);
            }
            int nloc = w * 32 + g * 16 + l15;
            float mown = fmaxf(fmaxf(lg[0], lg[1]), fmaxf(lg[2], lg[3]));
            float m8 = fmaxf(mown, __shfl_xor(mown, 16));
            float p0 = __expf(lg[0] - m8), p1 = __expf(lg[1] - m8);
            float p2 = __expf(lg[2] - m8), p3 = __expf(lg[3] - m8);
            float sown = p0 + p1 + p2 + p3;
            float inv = 1.0f / (sown + __shfl_xor(sown, 16));
            if (q < 2) {
                ushort_t u0 = f2bf(p0 * inv), u1 = f2bf(p1 * inv);
                ushort_t u2 = f2bf(p2 * inv), u3 = f2bf(p3 * inv);
                int s0 = q * 4;
                ps[(s0 + 0) * KS_S + nloc] = u0;
                ps[(s0 + 1) * KS_S + nloc] = u1;
                ps[(s0 + 2) * KS_S + nloc] = u2;
                ps[(s0 + 3) * KS_S + nloc] = u3;
                nacc[0] += bf2f(u0); nacc[1] += bf2f(u1);
                nacc[2] += bf2f(u2); nacc[3] += bf2f(u3);
            }
        }
        __syncthreads();

        bf16x8 pa[4];
        #pragma unroll
        for (int c = 0; c < 4; ++c)
            pa[c] = *(const bf16x8*)&ps[l15 * KS_S + c * 32 + q * 8];

        #pragma unroll
        for (int g2 = 0; g2 < 2; ++g2) {
            int dgrp = w * 2 + g2;
            #pragma unroll
            for (int c = 0; c < 4; ++c) {
                int nc = chunk * 16 + nt * 4 + c;
                bf16x8 bv = *(const bf16x8*)&vtbuf[(((size_t)b * 8 + dgrp) * 128 + nc) * 512 + lane * 8];
                acc[g2] = __builtin_amdgcn_mfma_f32_16x16x32_bf16(pa[c], bv, acc[g2], 0, 0, 0);
            }
        }
    }

    if (q < 2) {
        #pragma unroll
        for (int r = 0; r < 4; ++r) {
            float v = nacc[r];
            v += __shfl_xor(v, 1); v += __shfl_xor(v, 2);
            v += __shfl_xor(v, 4); v += __shfl_xor(v, 8);
            if (l15 == 0) atomicAdd(&nsh[q * 4 + r], v);
        }
        #pragma unroll
        for (int g2 = 0; g2 < 2; ++g2) {
            int d = w * 32 + g2 * 16 + l15;
            #pragma unroll
            for (int r = 0; r < 4; ++r)
                upart[((size_t)(chunk * 64 + b) * 8 + q * 4 + r) * 128 + d] = acc[g2][r];
        }
    }
    __syncthreads();
    if (t < 8) npart[chunk * 512 + b * 8 + t] = nsh[t];
}

// ---------------------------------------------------------------------------
// K4: sum partials -> GRU -> LN -> MLP -> residual (+ fused next-iter q).
// 512 blocks x 256 thr, one (b,s) row per block.
__global__ __launch_bounds__(256) void k_update3(
    const float* __restrict__ slots,
    const float* __restrict__ upart, const float* __restrict__ npart,
    const float* __restrict__ wih, const float* __restrict__ whh,
    const float* __restrict__ bih, const float* __restrict__ bhh,
    const float* __restrict__ mlg, const float* __restrict__ mlb,
    const float* __restrict__ w1, const float* __restrict__ b1,
    const float* __restrict__ w2, const float* __restrict__ b2,
    const float* __restrict__ ns_g, const float* __restrict__ ns_b,
    const float* __restrict__ wq, const float* __restrict__ bq,
    float* __restrict__ outp, ushort_t* __restrict__ qb, int do_q)
{
    __shared__ float us[128];
    __shared__ float hs[128];
    __shared__ float gs[768];
    __shared__ float hnw[128];
    __shared__ float lns[128];
    __shared__ float h1s[256];
    const int t = threadIdx.x;
    const int bs = blockIdx.x;  // 0..511

    if (t < 128) {
        float u = 0.f;
        #pragma unroll
        for (int c = 0; c < 8; ++c) u += upart[((size_t)(c * 512 + bs)) * 128 + t];
        float nsum = 0.f;
        #pragma unroll
        for (int c = 0; c < 8; ++c) nsum += npart[c * 512 + bs];
        us[t] = u / fmaxf(nsum, 1e-8f);
        hs[t] = slots[(size_t)bs * Dn + t];
    }
    __syncthreads();

    #pragma unroll
    for (int jj = 0; jj < 3; ++jj) {
        int j = t + jj * 256;
        const float* W = (j < 384) ? (wih + (size_t)j * Dn) : (whh + (size_t)(j - 384) * Dn);
        const float* X = (j < 384) ? us : hs;
        float a = 0.f;
        #pragma unroll 8
        for (int d = 0; d < 128; d += 4)
            a += dot4(*(const float4*)(W + d), *(const float4*)(X + d));
        gs[j] = a;
    }
    __syncthreads();

    if (t < 64) {
        float hnew[2];
        #pragma unroll
        for (int e = 0; e < 2; ++e) {
            int i = t + e * 64;
            float ir = gs[i]       + bih[i],       hr = gs[384 + i] + bhh[i];
            float iz = gs[128 + i] + bih[128 + i], hz = gs[512 + i] + bhh[128 + i];
            float in_= gs[256 + i] + bih[256 + i], hn = gs[640 + i] + bhh[256 + i];
            float r = 1.0f / (1.0f + __expf(-(ir + hr)));
            float z = 1.0f / (1.0f + __expf(-(iz + hz)));
            float n = tanhf(in_ + r * hn);
            hnew[e] = (1.0f - z) * n + z * hs[i];
        }
        float s  = hnew[0] + hnew[1];
        float sq = hnew[0]*hnew[0] + hnew[1]*hnew[1];
        #pragma unroll
        for (int m = 1; m <= 32; m <<= 1) { s += __shfl_xor(s, m); sq += __shfl_xor(sq, m); }
        float mu = s * (1.0f / 128.0f);
        float rs = rsqrtf(sq * (1.0f / 128.0f) - mu * mu + LN_EPS);
        #pragma unroll
        for (int e = 0; e < 2; ++e) {
            int i = t + e * 64;
            hnw[i] = hnew[e];
            lns[i] = (hnew[e] - mu) * rs * mlg[i] + mlb[i];
        }
    }
    __syncthreads();

    {
        const float* W = w1 + (size_t)t * Dn;
        float a = 0.f;
        #pragma unroll 8
        for (int d = 0; d < 128; d += 4)
            a += dot4(*(const float4*)(W + d), *(const float4*)&lns[d]);
        float x = a + b1[t];
        h1s[t] = 0.5f * x * (1.0f + erff(x * 0.70710678118654752f));
    }
    __syncthreads();

    if (t < 128) {
        const float* W = w2 + (size_t)t * Hn;
        float a = 0.f;
        #pragma unroll 8
        for (int d = 0; d < 256; d += 4)
            a += dot4(*(const float4*)(W + d), *(const float4*)&h1s[d]);
        float o = hnw[t] + a + b2[t];
        outp[(size_t)bs * Dn + t] = o;
        us[t] = o;  // reuse for q-LN
    }
    if (do_q) {
        __syncthreads();
        if (t < 64) {
            float v0 = us[t], v1 = us[t + 64];
            float s  = v0 + v1;
            float sq = v0*v0 + v1*v1;
            #pragma unroll
            for (int m = 1; m <= 32; m <<= 1) { s += __shfl_xor(s, m); sq += __shfl_xor(sq, m); }
            float mu = s * (1.0f / 128.0f);
            float rs = rsqrtf(sq * (1.0f / 128.0f) - mu * mu + LN_EPS);
            lns[t]      = (v0 - mu) * rs * ns_g[t]      + ns_b[t];
            lns[t + 64] = (v1 - mu) * rs * ns_g[t + 64] + ns_b[t + 64];
        }
        __syncthreads();
        if (t < 128) {
            const float* W = wq + (size_t)t * Dn;
            float a = 0.f;
            #pragma unroll 8
            for (int d = 0; d < 128; d += 4)
                a += dot4(*(const float4*)(W + d), *(const float4*)&lns[d]);
            qb[(size_t)bs * Dn + t] = f2bf((a + bq[t]) * QSCALE);
        }
    }
}

// ---------------------------------------------------------------------------
extern "C" void kernel_launch(void* const* d_in, const int* in_sizes, int n_in,
                              void* d_out, int out_size, void* d_ws, size_t ws_size,
                              hipStream_t stream) {
    (void)in_sizes; (void)n_in; (void)out_size; (void)ws_size;
    const float* inputs   = (const float*)d_in[0];
    const float* noise    = (const float*)d_in[1];
    const float* slots_mu = (const float*)d_in[2];
    const float* slots_ls = (const float*)d_in[3];
    const float* wq  = (const float*)d_in[4];
    const float* bq  = (const float*)d_in[5];
    const float* wk  = (const float*)d_in[6];
    const float* bk  = (const float*)d_in[7];
    const float* wv  = (const float*)d_in[8];
    const float* bv  = (const float*)d_in[9];
    const float* gwih = (const float*)d_in[10];
    const float* gwhh = (const float*)d_in[11];
    const float* gbih = (const float*)d_in[12];
    const float* gbhh = (const float*)d_in[13];
    const float* ns_g = (const float*)d_in[14];
    const float* ns_b = (const float*)d_in[15];
    const float* ni_g = (const float*)d_in[16];
    const float* ni_b = (const float*)d_in[17];
    const float* mlg  = (const float*)d_in[18];
    const float* mlb  = (const float*)d_in[19];
    const float* mw1  = (const float*)d_in[20];
    const float* mb1  = (const float*)d_in[21];
    const float* mw2  = (const float*)d_in[22];
    const float* mb2  = (const float*)d_in[23];

    float* ws      = (float*)d_ws;
    float* slots   = ws;                           // 65536 f
    float* upart   = ws + 65536;                   // 8*512*128 = 524288 f
    float* npart   = ws + 590336;                  // 4096 f
    ushort_t* qb    = (ushort_t*)(ws + 594432);    // 65536 bf16
    ushort_t* wallT = (ushort_t*)(ws + 627200);    // 32768 bf16
    ushort_t* kbuf  = (ushort_t*)(ws + 655360);    // 33554432 bf16 (frag order)
    ushort_t* vtbuf = (ushort_t*)(ws + 655360 + 16777216);  // 33554432 bf16

    k_slots_init<<<4, 256, 0, stream>>>(slots_mu, slots_ls, noise, slots);
    k_wprep<<<128, 256, 0, stream>>>(wk, wv, wallT);
    k_lnkv_mfma<<<4096, 256, 0, stream>>>(inputs, ni_g, ni_b, wallT, bk, bv, kbuf, vtbuf);
    k_qproj2<<<64, 256, 0, stream>>>(slots, ns_g, ns_b, wq, bq, qb);
    for (int iter = 0; iter < 3; ++iter) {
        k_attn_mfma<<<dim3(8, 64), 256, 0, stream>>>(kbuf, vtbuf, qb, upart, npart);
        float* outp = (iter == 2) ? (float*)d_out : slots;
        k_update3<<<512, 256, 0, stream>>>(slots, upart, npart, gwih, gwhh, gbih, gbhh,
                                           mlg, mlb, mw1, mb1, mw2, mb2, ns_g, ns_b, wq, bq,
                                           outp, qb, (iter == 2) ? 0 : 1);
    }
}

// Round 7
// 471.566 us; speedup vs baseline: 2.1229x; 1.0207x over previous
//
#include <hip/hip_runtime.h>
#include <hip/hip_bf16.h>
#include <math.h>

#define Bn 64
#define Nn 4096
#define Dn 128
#define Sn 8
#define Hn 256
#define LN_EPS 1e-5f
#define QSCALE 0.08838834764831845f  // 1/sqrt(128), pre-applied to q

typedef __bf16 bf16x8 __attribute__((ext_vector_type(8)));
typedef float f32x4 __attribute__((ext_vector_type(4)));
typedef unsigned short ushort_t;

__device__ __forceinline__ float dot4(float4 a, float4 b) {
    return a.x*b.x + a.y*b.y + a.z*b.z + a.w*b.w;
}
__device__ __forceinline__ ushort_t f2bf(float f) {
    __bf16 b = (__bf16)f;
    ushort_t u; __builtin_memcpy(&u, &b, 2); return u;
}
__device__ __forceinline__ float bf2f(ushort_t u) {
    unsigned int x = ((unsigned int)u) << 16; float f; __builtin_memcpy(&f, &x, 4); return f;
}
__device__ __forceinline__ bf16x8 zero8() {
    bf16x8 z;
    #pragma unroll
    for (int i = 0; i < 8; ++i) z[i] = (__bf16)0.0f;
    return z;
}

// ---------------------------------------------------------------------------
// K0: slots = mu + exp(log_sigma) * noise, broadcast over batch
__global__ void k_slots_init(const float* __restrict__ mu, const float* __restrict__ ls,
                             const float* __restrict__ noise, float* __restrict__ slots) {
    int i = blockIdx.x * blockDim.x + threadIdx.x;
    if (i < Sn * Dn) {
        float v = mu[i] + __expf(ls[i]) * noise[i];
        #pragma unroll 4
        for (int b = 0; b < Bn; ++b) slots[b * Sn * Dn + i] = v;
    }
}

// ---------------------------------------------------------------------------
// Kw: pack [wk; wv] -> bf16 in MFMA A-fragment order
__global__ void k_wprep(const float* __restrict__ wk, const float* __restrict__ wv,
                        ushort_t* __restrict__ wallT) {
    int o = blockIdx.x * blockDim.x + threadIdx.x;  // 32768
    if (o < 32768) {
        int e = o & 7;
        int l = (o >> 3) & 15;
        int q = (o >> 7) & 3;
        int k = (o >> 9) & 3;
        int G = o >> 11;
        int row = G * 16 + l;
        int col = k * 32 + q * 8 + e;
        float f = (row < 128) ? wk[row * 128 + col] : wv[(row - 128) * 128 + col];
        wallT[o] = f2bf(f);
    }
}

// ---------------------------------------------------------------------------
// K1: LN + K/V projection. ZERO LDS / ZERO BARRIERS: each wave owns 16 rows.
// Lane (q,l15) of wave w loads x[row = rowbase+w*16+l15][d = c*32+q*8+e] --
// exactly its MFMA B-fragment footprint. LN stats via shfl_xor(16/32) across
// quads. Outputs in MFMA fragment order, coalesced stores.
__global__ __launch_bounds__(256) void k_lnkv_mfma(
    const float* __restrict__ inp, const float* __restrict__ ni_g, const float* __restrict__ ni_b,
    const ushort_t* __restrict__ wallT, const float* __restrict__ bk, const float* __restrict__ bv,
    ushort_t* __restrict__ kout, ushort_t* __restrict__ vout)
{
    const int t = threadIdx.x;
    const int lane = t & 63;
    const int w = t >> 6;
    const int l15 = lane & 15, q = lane >> 4;
    const int rowbase = blockIdx.x * 64;           // 4096 blocks
    const int row = rowbase + w * 16 + l15;
    const int b_idx = rowbase >> 12;

    const float* xr = inp + (size_t)row * Dn + q * 8;
    float4 xv[8];
    #pragma unroll
    for (int c = 0; c < 4; ++c) {
        xv[2*c]   = *(const float4*)(xr + c * 32);
        xv[2*c+1] = *(const float4*)(xr + c * 32 + 4);
    }
    float s = 0.f, sq = 0.f;
    #pragma unroll
    for (int i = 0; i < 8; ++i) {
        float4 x4 = xv[i];
        s  += x4.x + x4.y + x4.z + x4.w;
        sq += x4.x*x4.x + x4.y*x4.y + x4.z*x4.z + x4.w*x4.w;
    }
    s  += __shfl_xor(s, 16);  s  += __shfl_xor(s, 32);
    sq += __shfl_xor(sq, 16); sq += __shfl_xor(sq, 32);
    float mu = s * (1.0f / 128.0f);
    float rs = rsqrtf(sq * (1.0f / 128.0f) - mu * mu + LN_EPS);

    // normalize into B-fragments (lane already holds exactly frag footprint)
    bf16x8 xf[4];
    #pragma unroll
    for (int c = 0; c < 4; ++c) {
        const float* gp = ni_g + c * 32 + q * 8;
        const float* bp = ni_b + c * 32 + q * 8;
        float4 g0 = *(const float4*)gp, g1 = *(const float4*)(gp + 4);
        float4 b0 = *(const float4*)bp, b1 = *(const float4*)(bp + 4);
        bf16x8 f;
        f[0] = (__bf16)((xv[2*c].x   - mu) * rs * g0.x + b0.x);
        f[1] = (__bf16)((xv[2*c].y   - mu) * rs * g0.y + b0.y);
        f[2] = (__bf16)((xv[2*c].z   - mu) * rs * g0.z + b0.z);
        f[3] = (__bf16)((xv[2*c].w   - mu) * rs * g0.w + b0.w);
        f[4] = (__bf16)((xv[2*c+1].x - mu) * rs * g1.x + b1.x);
        f[5] = (__bf16)((xv[2*c+1].y - mu) * rs * g1.y + b1.y);
        f[6] = (__bf16)((xv[2*c+1].z - mu) * rs * g1.z + b1.z);
        f[7] = (__bf16)((xv[2*c+1].w - mu) * rs * g1.w + b1.w);
        xf[c] = f;
    }

    const int nloc0 = (rowbase & 4095) + w * 16 + q * 4;
    #pragma unroll
    for (int ct = 0; ct < 16; ++ct) {
        bf16x8 af[4];
        #pragma unroll
        for (int k4 = 0; k4 < 4; ++k4)
            af[k4] = *(const bf16x8*)&wallT[(size_t)((ct * 4 + k4) * 64 + lane) * 8];
        f32x4 acc = {0.f, 0.f, 0.f, 0.f};
        if (ct < 8) {
            #pragma unroll
            for (int k4 = 0; k4 < 4; ++k4)
                acc = __builtin_amdgcn_mfma_f32_16x16x32_bf16(af[k4], xf[k4], acc, 0, 0, 0);
            // lane stores k[n=row][d0..d0+3], d0 = ct*16 + q*4
            int d0 = ct * 16 + q * 4;
            float4 bia = *(const float4*)&bk[d0];
            ushort4 o = { f2bf(acc[0] + bia.x), f2bf(acc[1] + bia.y),
                          f2bf(acc[2] + bia.z), f2bf(acc[3] + bia.w) };
            size_t off = ((size_t)(((rowbase >> 4) + w) * 4 + (d0 >> 5)) * 64
                          + ((d0 >> 3) & 3) * 16 + l15) * 8 + (d0 & 7);
            *(ushort4*)&kout[off] = o;
        } else {
            #pragma unroll
            for (int k4 = 0; k4 < 4; ++k4)
                acc = __builtin_amdgcn_mfma_f32_16x16x32_bf16(xf[k4], af[k4], acc, 0, 0, 0);
            // lane stores v[d = dgrp*16+l15][n0..n0+3], n0 = nloc0
            int dgrp = ct - 8;
            float bb = bv[dgrp * 16 + l15];
            ushort4 o = { f2bf(acc[0] + bb), f2bf(acc[1] + bb),
                          f2bf(acc[2] + bb), f2bf(acc[3] + bb) };
            size_t off = (((size_t)(b_idx * 8 + dgrp) * 128 + (nloc0 >> 5)) * 64
                          + ((nloc0 >> 3) & 3) * 16 + l15) * 8 + (nloc0 & 7);
            *(ushort4*)&vout[off] = o;
        }
    }
}

// ---------------------------------------------------------------------------
// K2: initial q = LN(slots)@wq.T + bq, bf16 pre-scaled. 64 blocks x 256 thr.
__global__ __launch_bounds__(256) void k_qproj2(
    const float* __restrict__ slots, const float* __restrict__ ns_g, const float* __restrict__ ns_b,
    const float* __restrict__ wq, const float* __restrict__ bq,
    ushort_t* __restrict__ qb)
{
    __shared__ float lnq[8][128];
    const int t = threadIdx.x;
    const int bs0 = blockIdx.x * 8;
    {
        int r = t >> 5, c = (t & 31) * 4;
        float4 x4 = *(const float4*)&slots[(size_t)(bs0 + r) * Dn + c];
        float s  = x4.x + x4.y + x4.z + x4.w;
        float sq = x4.x*x4.x + x4.y*x4.y + x4.z*x4.z + x4.w*x4.w;
        #pragma unroll
        for (int m = 1; m <= 16; m <<= 1) { s += __shfl_xor(s, m); sq += __shfl_xor(sq, m); }
        float mu = s * (1.0f / 128.0f);
        float rs = rsqrtf(sq * (1.0f / 128.0f) - mu * mu + LN_EPS);
        lnq[r][c+0] = (x4.x - mu) * rs * ns_g[c+0] + ns_b[c+0];
        lnq[r][c+1] = (x4.y - mu) * rs * ns_g[c+1] + ns_b[c+1];
        lnq[r][c+2] = (x4.z - mu) * rs * ns_g[c+2] + ns_b[c+2];
        lnq[r][c+3] = (x4.w - mu) * rs * ns_g[c+3] + ns_b[c+3];
    }
    __syncthreads();
    {
        int c = t & 127, rb = (t >> 7) * 4;
        const float* W = wq + (size_t)c * Dn;
        float acc[4] = {0.f, 0.f, 0.f, 0.f};
        for (int d = 0; d < 128; d += 4) {
            float4 w4 = *(const float4*)(W + d);
            #pragma unroll
            for (int rr = 0; rr < 4; ++rr) acc[rr] += dot4(w4, *(const float4*)&lnq[rb + rr][d]);
        }
        float bb = bq[c];
        #pragma unroll
        for (int rr = 0; rr < 4; ++rr)
            qb[(size_t)(bs0 + rb + rr) * Dn + c] = f2bf((acc[rr] + bb) * QSCALE);
    }
}

// ---------------------------------------------------------------------------
// K3: MFMA attention, barrier-free waves. grid (8 chunks, 64 b), 512 thr
// (8 waves), each wave owns 64 n. QK operand-swapped (D[n][s]); softmax over
// s via shfl_xor(1/2/4); P->A-operand via in-register shuffle transpose;
// PV partials per wave; ONE final LDS reduction.
__global__ __launch_bounds__(512) void k_attn_mfma(
    const ushort_t* __restrict__ kbuf, const ushort_t* __restrict__ vtbuf,
    const ushort_t* __restrict__ qb,
    float* __restrict__ upart, float* __restrict__ npart)
{
    __shared__ float ush[8][8][128];   // 32 KiB
    __shared__ float nsh[8][8];
    const int t = threadIdx.x;
    const int b = blockIdx.y;
    const int chunk = blockIdx.x;      // 0..7
    const int lane = t & 63;
    const int w = t >> 6;
    const int l15 = lane & 15, q = lane >> 4;
    const int srcA = ((lane & 16) << 1) | l15;   // 32*(qt&1) + l15
    const bool hi = lane >= 32;                  // qt>>1

    bf16x8 aq[4];
    #pragma unroll
    for (int c = 0; c < 4; ++c) {
        bf16x8 z = zero8();
        if (l15 < 8)
            z = *(const bf16x8*)&qb[((size_t)b * Sn + l15) * Dn + c * 32 + q * 8];
        aq[c] = z;
    }

    f32x4 acc[8];
    #pragma unroll
    for (int dg = 0; dg < 8; ++dg) acc[dg] = (f32x4){0.f, 0.f, 0.f, 0.f};
    float nacc = 0.f;

    #pragma unroll
    for (int u = 0; u < 2; ++u) {
        const int n32 = chunk * 512 + w * 64 + u * 32;   // n within batch
        const int ng = n32 >> 4;
        float p0[4], p1[4];
        #pragma unroll
        for (int T = 0; T < 2; ++T) {
            f32x4 lg = {0.f, 0.f, 0.f, 0.f};
            #pragma unroll
            for (int c = 0; c < 4; ++c) {
                bf16x8 kf = *(const bf16x8*)&kbuf[(((size_t)b * 256 + ng + T) * 4 + c) * 512 + lane * 8];
                lg = __builtin_amdgcn_mfma_f32_16x16x32_bf16(kf, aq[c], lg, 0, 0, 0);
            }
            // lane: n = T*16 + q*4 + r, s = l15 (cols 8..15 zero-pad, benign)
            float* pp = T ? p1 : p0;
            #pragma unroll
            for (int r = 0; r < 4; ++r) {
                float m = lg[r];
                m = fmaxf(m, __shfl_xor(m, 1));
                m = fmaxf(m, __shfl_xor(m, 2));
                m = fmaxf(m, __shfl_xor(m, 4));
                float p = __expf(lg[r] - m);
                float ss = p;
                ss += __shfl_xor(ss, 1); ss += __shfl_xor(ss, 2); ss += __shfl_xor(ss, 4);
                pp[r] = p * (1.0f / ss);
            }
        }
        // in-register transpose: pa[e] = p[s=l15][n = 8*qt + e]
        float paf[8];
        #pragma unroll
        for (int r = 0; r < 4; ++r) {
            float a0 = __shfl(p0[r], srcA);
            float a1 = __shfl(p1[r], srcA);
            float c0 = __shfl(p0[r], srcA + 16);
            float c1 = __shfl(p1[r], srcA + 16);
            paf[r]     = hi ? a1 : a0;
            paf[r + 4] = hi ? c1 : c0;
        }
        bf16x8 pa;
        #pragma unroll
        for (int e = 0; e < 8; ++e) {
            __bf16 bb = (__bf16)paf[e];
            pa[e] = bb;
            nacc += (float)bb;   // rounded p for norm consistency with PV
        }
        const int nc = n32 >> 5;
        #pragma unroll
        for (int dg = 0; dg < 8; ++dg) {
            bf16x8 bv = *(const bf16x8*)&vtbuf[(((size_t)b * 8 + dg) * 128 + nc) * 512 + lane * 8];
            acc[dg] = __builtin_amdgcn_mfma_f32_16x16x32_bf16(pa, bv, acc[dg], 0, 0, 0);
        }
    }

    // norm: sum across quads (same l15 = slot)
    nacc += __shfl_xor(nacc, 16);
    nacc += __shfl_xor(nacc, 32);
    if (lane < 8) nsh[w][lane] = nacc;
    // PV D layout: lane holds slots q*4+r (q<2 real) at d = dg*16 + l15
    if (q < 2) {
        #pragma unroll
        for (int dg = 0; dg < 8; ++dg)
            #pragma unroll
            for (int r = 0; r < 4; ++r)
                ush[w][q * 4 + r][dg * 16 + l15] = acc[dg][r];
    }
    __syncthreads();
    if (t < 256) {
        int s = t >> 5, d0 = (t & 31) * 4;
        float4 sum = {0.f, 0.f, 0.f, 0.f};
        #pragma unroll
        for (int w8 = 0; w8 < 8; ++w8) {
            float4 vv = *(const float4*)&ush[w8][s][d0];
            sum.x += vv.x; sum.y += vv.y; sum.z += vv.z; sum.w += vv.w;
        }
        *(float4*)&upart[((size_t)chunk * 512 + b * 8 + s) * 128 + d0] = sum;
    }
    if (t < 8) {
        float sn = 0.f;
        #pragma unroll
        for (int w8 = 0; w8 < 8; ++w8) sn += nsh[w8][t];
        npart[chunk * 512 + b * 8 + t] = sn;
    }
}

// ---------------------------------------------------------------------------
// K4: sum partials -> GRU -> LN -> MLP -> residual (+ fused next-iter q).
// 512 blocks x 256 thr, one (b,s) row per block.
__global__ __launch_bounds__(256) void k_update3(
    const float* __restrict__ slots,
    const float* __restrict__ upart, const float* __restrict__ npart,
    const float* __restrict__ wih, const float* __restrict__ whh,
    const float* __restrict__ bih, const float* __restrict__ bhh,
    const float* __restrict__ mlg, const float* __restrict__ mlb,
    const float* __restrict__ w1, const float* __restrict__ b1,
    const float* __restrict__ w2, const float* __restrict__ b2,
    const float* __restrict__ ns_g, const float* __restrict__ ns_b,
    const float* __restrict__ wq, const float* __restrict__ bq,
    float* __restrict__ outp, ushort_t* __restrict__ qb, int do_q)
{
    __shared__ float us[128];
    __shared__ float hs[128];
    __shared__ float gs[768];
    __shared__ float hnw[128];
    __shared__ float lns[128];
    __shared__ float h1s[256];
    const int t = threadIdx.x;
    const int bs = blockIdx.x;  // 0..511

    if (t < 128) {
        float u = 0.f;
        #pragma unroll
        for (int c = 0; c < 8; ++c) u += upart[((size_t)(c * 512 + bs)) * 128 + t];
        float nsum = 0.f;
        #pragma unroll
        for (int c = 0; c < 8; ++c) nsum += npart[c * 512 + bs];
        us[t] = u / fmaxf(nsum, 1e-8f);
        hs[t] = slots[(size_t)bs * Dn + t];
    }
    __syncthreads();

    #pragma unroll
    for (int jj = 0; jj < 3; ++jj) {
        int j = t + jj * 256;
        const float* W = (j < 384) ? (wih + (size_t)j * Dn) : (whh + (size_t)(j - 384) * Dn);
        const float* X = (j < 384) ? us : hs;
        float a = 0.f;
        #pragma unroll 8
        for (int d = 0; d < 128; d += 4)
            a += dot4(*(const float4*)(W + d), *(const float4*)(X + d));
        gs[j] = a;
    }
    __syncthreads();

    if (t < 64) {
        float hnew[2];
        #pragma unroll
        for (int e = 0; e < 2; ++e) {
            int i = t + e * 64;
            float ir = gs[i]       + bih[i],       hr = gs[384 + i] + bhh[i];
            float iz = gs[128 + i] + bih[128 + i], hz = gs[512 + i] + bhh[128 + i];
            float in_= gs[256 + i] + bih[256 + i], hn = gs[640 + i] + bhh[256 + i];
            float r = 1.0f / (1.0f + __expf(-(ir + hr)));
            float z = 1.0f / (1.0f + __expf(-(iz + hz)));
            float n = tanhf(in_ + r * hn);
            hnew[e] = (1.0f - z) * n + z * hs[i];
        }
        float s  = hnew[0] + hnew[1];
        float sq = hnew[0]*hnew[0] + hnew[1]*hnew[1];
        #pragma unroll
        for (int m = 1; m <= 32; m <<= 1) { s += __shfl_xor(s, m); sq += __shfl_xor(sq, m); }
        float mu = s * (1.0f / 128.0f);
        float rs = rsqrtf(sq * (1.0f / 128.0f) - mu * mu + LN_EPS);
        #pragma unroll
        for (int e = 0; e < 2; ++e) {
            int i = t + e * 64;
            hnw[i] = hnew[e];
            lns[i] = (hnew[e] - mu) * rs * mlg[i] + mlb[i];
        }
    }
    __syncthreads();

    {
        const float* W = w1 + (size_t)t * Dn;
        float a = 0.f;
        #pragma unroll 8
        for (int d = 0; d < 128; d += 4)
            a += dot4(*(const float4*)(W + d), *(const float4*)&lns[d]);
        float x = a + b1[t];
        h1s[t] = 0.5f * x * (1.0f + erff(x * 0.70710678118654752f));
    }
    __syncthreads();

    if (t < 128) {
        const float* W = w2 + (size_t)t * Hn;
        float a = 0.f;
        #pragma unroll 8
        for (int d = 0; d < 256; d += 4)
            a += dot4(*(const float4*)(W + d), *(const float4*)&h1s[d]);
        float o = hnw[t] + a + b2[t];
        outp[(size_t)bs * Dn + t] = o;
        us[t] = o;  // reuse for q-LN
    }
    if (do_q) {
        __syncthreads();
        if (t < 64) {
            float v0 = us[t], v1 = us[t + 64];
            float s  = v0 + v1;
            float sq = v0*v0 + v1*v1;
            #pragma unroll
            for (int m = 1; m <= 32; m <<= 1) { s += __shfl_xor(s, m); sq += __shfl_xor(sq, m); }
            float mu = s * (1.0f / 128.0f);
            float rs = rsqrtf(sq * (1.0f / 128.0f) - mu * mu + LN_EPS);
            lns[t]      = (v0 - mu) * rs * ns_g[t]      + ns_b[t];
            lns[t + 64] = (v1 - mu) * rs * ns_g[t + 64] + ns_b[t + 64];
        }
        __syncthreads();
        if (t < 128) {
            const float* W = wq + (size_t)t * Dn;
            float a = 0.f;
            #pragma unroll 8
            for (int d = 0; d < 128; d += 4)
                a += dot4(*(const float4*)(W + d), *(const float4*)&lns[d]);
            qb[(size_t)bs * Dn + t] = f2bf((a + bq[t]) * QSCALE);
        }
    }
}

// ---------------------------------------------------------------------------
extern "C" void kernel_launch(void* const* d_in, const int* in_sizes, int n_in,
                              void* d_out, int out_size, void* d_ws, size_t ws_size,
                              hipStream_t stream) {
    (void)in_sizes; (void)n_in; (void)out_size; (void)ws_size;
    const float* inputs   = (const float*)d_in[0];
    const float* noise    = (const float*)d_in[1];
    const float* slots_mu = (const float*)d_in[2];
    const float* slots_ls = (const float*)d_in[3];
    const float* wq  = (const float*)d_in[4];
    const float* bq  = (const float*)d_in[5];
    const float* wk  = (const float*)d_in[6];
    const float* bk  = (const float*)d_in[7];
    const float* wv  = (const float*)d_in[8];
    const float* bv  = (const float*)d_in[9];
    const float* gwih = (const float*)d_in[10];
    const float* gwhh = (const float*)d_in[11];
    const float* gbih = (const float*)d_in[12];
    const float* gbhh = (const float*)d_in[13];
    const float* ns_g = (const float*)d_in[14];
    const float* ns_b = (const float*)d_in[15];
    const float* ni_g = (const float*)d_in[16];
    const float* ni_b = (const float*)d_in[17];
    const float* mlg  = (const float*)d_in[18];
    const float* mlb  = (const float*)d_in[19];
    const float* mw1  = (const float*)d_in[20];
    const float* mb1  = (const float*)d_in[21];
    const float* mw2  = (const float*)d_in[22];
    const float* mb2  = (const float*)d_in[23];

    float* ws      = (float*)d_ws;
    float* slots   = ws;                            // 0 .. 65536
    float* upart   = ws + 65536;                    // 65536 .. 589824 (8*512*128)
    float* npart   = ws + 589824;                   // 589824 .. 593920 (4096)
    ushort_t* qb    = (ushort_t*)(ws + 593920);     // 65536 bf16 (32768 f)
    ushort_t* wallT = (ushort_t*)(ws + 626688);     // 32768 bf16 (16384 f)
    ushort_t* kbuf  = (ushort_t*)(ws + 643072);     // 33554432 bf16 (frag order)
    ushort_t* vtbuf = kbuf + 33554432;              // 33554432 bf16 (frag order)

    k_slots_init<<<4, 256, 0, stream>>>(slots_mu, slots_ls, noise, slots);
    k_wprep<<<128, 256, 0, stream>>>(wk, wv, wallT);
    k_lnkv_mfma<<<4096, 256, 0, stream>>>(inputs, ni_g, ni_b, wallT, bk, bv, kbuf, vtbuf);
    k_qproj2<<<64, 256, 0, stream>>>(slots, ns_g, ns_b, wq, bq, qb);
    for (int iter = 0; iter < 3; ++iter) {
        k_attn_mfma<<<dim3(8, 64), 512, 0, stream>>>(kbuf, vtbuf, qb, upart, npart);
        float* outp = (iter == 2) ? (float*)d_out : slots;
        k_update3<<<512, 256, 0, stream>>>(slots, upart, npart, gwih, gwhh, gbih, gbhh,
                                           mlg, mlb, mw1, mb1, mw2, mb2, ns_g, ns_b, wq, bq,
                                           outp, qb, (iter == 2) ? 0 : 1);
    }
}